// Round 9
// baseline (138.528 us; speedup 1.0000x reference)
//
#include <hip/hip_runtime.h>
#include <math.h>

// B=4, K=256, D=128, H=4, alpha=0.2
// leaky(s) = 0.6*s + 0.4*|s|  (exact for alpha=0.2)
// e_ij = [0.6*(a.Lp_i) cancels in softmax] + 0.6*(a.R_j) + sum_d (0.4 a_d)|Lp_id + R_jd| + bias_ij
// mean_h(P_h @ x) = (mean_h P_h) @ x.
// k2 writes 0.25*P per head (bf16); the LAST block of each (b,it) group (device-scope
// atomic counter + threadfence) sums the 4 head planes and does the single PV -> out.
constexpr int Kc = 256, Dc = 128, Mc = 1024;    // Mc = B*K

typedef _Float16 h2_t __attribute__((ext_vector_type(2)));
union U32H2 { unsigned int u; h2_t h; };
__device__ inline h2_t u2h(unsigned int u) { U32H2 x; x.u = u; return x.h; }
__device__ inline unsigned int h2u(h2_t h) { U32H2 x; x.h = h; return x.u; }
__device__ inline unsigned int packh(float a, float b) {
    h2_t h; h.x = (_Float16)a; h.y = (_Float16)b; return h2u(h);
}
__device__ inline unsigned int f2bf(float f) {      // fp32 -> bf16 bits (RNE)
    unsigned int u = __float_as_uint(f);
    return (u + 0x7FFFu + ((u >> 16) & 1u)) >> 16;
}
__device__ inline float bf2f_lo(unsigned int u) { return __uint_as_float(u << 16); }
__device__ inline float bf2f_hi(unsigned int u) { return __uint_as_float(u & 0xFFFF0000u); }

// acc += (0.4a_2d)|l_2d + r_2d| + (0.4a_2d+1)|l_2d+1 + r_2d+1|, f32 accumulate
__device__ inline float estep(unsigned int r, unsigned int l, h2_t av, float acc) {
    h2_t s = u2h(r) + u2h(l);                       // v_pk_add_f16
    unsigned int t = h2u(s) & 0x7FFF7FFFu;          // packed abs
#if __has_builtin(__builtin_amdgcn_fdot2)
    return __builtin_amdgcn_fdot2(u2h(t), av, acc, false);   // v_dot2_f32_f16
#else
    h2_t th = u2h(t);
    return fmaf((float)th.x, (float)av.x, fmaf((float)th.y, (float)av.y, acc));
#endif
}

// ---------------------------------------------------------------------------
// K1 (512 blocks, 256 thr): 32x64-tile fp32 GEMM, 2x4 reg block.
//   bid <  256 : Lpp[h][m][dp] = packed-f16 pair of (x@W_src + lin_b)
//                + zero the (b,it) arrival counters (cnt[bid], bid<256)
//   bid >= 256 : Rtp[hb][dp][j] = packed-f16 pair of (x@W_dst)^T
//                + eb[(hb*4+dt)][j] = 1.5 * sum_{d in 32-slice} 0.4*a_d*R_jd (fp32)
// ---------------------------------------------------------------------------
__global__ __launch_bounds__(256) void k1(const float* __restrict__ x,
                                          const float* __restrict__ W,
                                          const float* __restrict__ lin_b,
                                          const float* __restrict__ a,
                                          unsigned int* __restrict__ Lpp,
                                          unsigned int* __restrict__ Rtp,
                                          float* __restrict__ eb,
                                          int* __restrict__ cnt) {
    __shared__ float As[128][32];   // [k][m-role] 16 KB
    __shared__ float Bs[128][64];   // [k][n-role] 32 KB
    __shared__ float red[4][16][4];

    const int tid = threadIdx.x;
    const int bid = blockIdx.x;
    const int tx = tid & 15, ty = tid >> 4;   // ty 0..15
    const bool isL = (bid < 256);

    if (isL && tid == 0) cnt[bid] = 0;        // re-zero every call (graph-safe)

    int h, b, m0, n0, dt;
    if (isL) {
        const int nt = bid & 1, mt = (bid >> 1) & 31;
        h = (bid >> 6) & 3;
        m0 = mt * 32; n0 = nt * 64; b = 0; dt = 0;
        {
            const int m_l = tid & 31, kq = tid >> 5;
            #pragma unroll
            for (int c = 0; c < 4; ++c) {
                const int k0 = kq * 16 + c * 4;
                const float4 v = *(const float4*)&x[(m0 + m_l) * Dc + k0];
                As[k0 + 0][m_l] = v.x; As[k0 + 1][m_l] = v.y;
                As[k0 + 2][m_l] = v.z; As[k0 + 3][m_l] = v.w;
            }
        }
        {
            const int n_l = tid & 63, kq = tid >> 6;
            const float* Wb = W + (h * 2) * Dc * Dc;
            #pragma unroll
            for (int kk = 0; kk < 32; ++kk) {
                const int k = kq * 32 + kk;
                Bs[k][n_l] = Wb[k * Dc + n0 + n_l];
            }
        }
    } else {
        const int r_ = bid - 256;
        const int jt = r_ & 3;
        dt = (r_ >> 2) & 3;
        b  = (r_ >> 4) & 3;
        h  = (r_ >> 6) & 3;
        m0 = dt * 32;          // m-role = d
        n0 = jt * 64;          // n-role = j
        {
            const int d_l = tid & 31, kq = tid >> 5;
            const float* Wb = W + ((h * 2 + 1) * Dc) * Dc;
            #pragma unroll
            for (int kk = 0; kk < 16; ++kk) {
                const int k = kq * 16 + kk;
                As[k][d_l] = Wb[k * Dc + m0 + d_l];
            }
        }
        {
            const int j_l = tid & 63, kq = tid >> 6;
            #pragma unroll
            for (int c = 0; c < 8; ++c) {
                const int k0 = kq * 32 + c * 4;
                const float4 v = *(const float4*)&x[(b * Kc + n0 + j_l) * Dc + k0];
                Bs[k0 + 0][j_l] = v.x; Bs[k0 + 1][j_l] = v.y;
                Bs[k0 + 2][j_l] = v.z; Bs[k0 + 3][j_l] = v.w;
            }
        }
    }
    __syncthreads();

    float acc[2][4];
    #pragma unroll
    for (int r = 0; r < 2; ++r)
        #pragma unroll
        for (int c = 0; c < 4; ++c) acc[r][c] = 0.f;

    #pragma unroll 16
    for (int k = 0; k < 128; ++k) {
        const float2 xa = *(const float2*)&As[k][ty * 2];
        const float4 wb = *(const float4*)&Bs[k][tx * 4];
        acc[0][0] = fmaf(xa.x, wb.x, acc[0][0]);
        acc[0][1] = fmaf(xa.x, wb.y, acc[0][1]);
        acc[0][2] = fmaf(xa.x, wb.z, acc[0][2]);
        acc[0][3] = fmaf(xa.x, wb.w, acc[0][3]);
        acc[1][0] = fmaf(xa.y, wb.x, acc[1][0]);
        acc[1][1] = fmaf(xa.y, wb.y, acc[1][1]);
        acc[1][2] = fmaf(xa.y, wb.z, acc[1][2]);
        acc[1][3] = fmaf(xa.y, wb.w, acc[1][3]);
    }

    if (isL) {
        const float4 lv = *(const float4*)&lin_b[h * Dc + n0 + tx * 4];
        #pragma unroll
        for (int r = 0; r < 2; ++r) {
            uint2 pk;
            pk.x = packh(acc[r][0] + lv.x, acc[r][1] + lv.y);
            pk.y = packh(acc[r][2] + lv.z, acc[r][3] + lv.w);
            *(uint2*)&Lpp[(h * Mc + m0 + ty * 2 + r) * 64 + (n0 >> 1) + tx * 2] = pk;
        }
    } else {
        {
            uint4 pk;
            pk.x = packh(acc[0][0], acc[1][0]);
            pk.y = packh(acc[0][1], acc[1][1]);
            pk.z = packh(acc[0][2], acc[1][2]);
            pk.w = packh(acc[0][3], acc[1][3]);
            *(uint4*)&Rtp[((h * 4 + b) * 64 + (m0 >> 1) + ty) * Kc + n0 + tx * 4] = pk;
        }
        const float2 av = *(const float2*)&a[h * Dc + m0 + ty * 2];
        float p0 = 0.4f * (av.x * acc[0][0] + av.y * acc[1][0]);
        float p1 = 0.4f * (av.x * acc[0][1] + av.y * acc[1][1]);
        float p2 = 0.4f * (av.x * acc[0][2] + av.y * acc[1][2]);
        float p3 = 0.4f * (av.x * acc[0][3] + av.y * acc[1][3]);
        p0 += __shfl_xor(p0, 16, 64); p0 += __shfl_xor(p0, 32, 64);
        p1 += __shfl_xor(p1, 16, 64); p1 += __shfl_xor(p1, 32, 64);
        p2 += __shfl_xor(p2, 16, 64); p2 += __shfl_xor(p2, 32, 64);
        p3 += __shfl_xor(p3, 16, 64); p3 += __shfl_xor(p3, 32, 64);
        if (((tid >> 4) & 3) == 0) {
            const int w = tid >> 6;
            red[w][tx][0] = p0; red[w][tx][1] = p1;
            red[w][tx][2] = p2; red[w][tx][3] = p3;
        }
        __syncthreads();
        if (tid < 64) {
            const int txl = tid >> 2, c = tid & 3;
            const float v = red[0][txl][c] + red[1][txl][c] + red[2][txl][c] + red[3][txl][c];
            eb[((h * 4 + b) * 4 + dt) * Kc + n0 + tid] = 1.5f * v;
        }
    }
}

// ---------------------------------------------------------------------------
// K2 (1024 blocks = (hb, 64 i-tiles of 4 rows), 256 thr, 4 blocks/CU,
// XCD-pinned): e-phase (dot2) -> dq-reduce -> softmax -> 0.25*P (bf16) to Pws.
// Then device-scope fence + arrival counter; the 4th (last) block of each
// (b,it) group sums the 4 head planes and runs the PV, writing final out.
// ---------------------------------------------------------------------------
__global__ __launch_bounds__(256) void k2(const float* __restrict__ x,
                                          const float* __restrict__ a,
                                          const float* __restrict__ bias,
                                          const unsigned int* __restrict__ Lpp,
                                          const unsigned int* __restrict__ Rtp,
                                          const float* __restrict__ eb,
                                          unsigned short* __restrict__ Pws,
                                          int* __restrict__ cnt,
                                          float* __restrict__ out) {
    __shared__ float red[256 * 20];        // 20 KB reduce scratch (e-phase, then PV)
    __shared__ unsigned int lpT2[64 * 4];  // [dp][i] 1 KB packed-f16 Lp
    __shared__ unsigned int aa2s[64];      // packed-f16 0.4*a pairs
    __shared__ float pbar4[4 * Kc];        // P-bar for the last-block PV (4 KB)
    __shared__ int lastFlag;

    const int tid = threadIdx.x;
    const int L = blockIdx.x;
    // XCD-pin: consecutive blockIdx round-robin across XCDs (heuristic).
    const int xcd = L & 7, q = L >> 3;       // q 0..127
    const int hb = (xcd << 1) | (q & 1);     // 2 planes per XCD
    const int it = q >> 1;                   // 0..63
    const int h = hb >> 2, b = hb & 3;
    const int i0 = it * 4;

    {
        const int i = tid & 3, dp = tid >> 2;
        lpT2[dp * 4 + i] = Lpp[(h * Mc + b * Kc + i0 + i) * 64 + dp];
    }
    if (tid < 64) aa2s[tid] = packh(0.4f * a[h * Dc + 2 * tid], 0.4f * a[h * Dc + 2 * tid + 1]);
    __syncthreads();

    const int dq = tid >> 6, j4 = tid & 63;
    float4 acc0 = make_float4(0.f, 0.f, 0.f, 0.f);
    float4 acc1 = make_float4(0.f, 0.f, 0.f, 0.f);
    float4 acc2 = make_float4(0.f, 0.f, 0.f, 0.f);
    float4 acc3 = make_float4(0.f, 0.f, 0.f, 0.f);
    {
        const unsigned int* rb = Rtp + (hb * 64 + dq * 16) * Kc + j4 * 4;
        const unsigned int* lt = lpT2 + dq * 16 * 4;
        const unsigned int* at = aa2s + dq * 16;
        #pragma unroll
        for (int dp = 0; dp < 16; ++dp) {
            const uint4 rr = *(const uint4*)(rb + dp * Kc);    // 4 j cols x 2 d (global, L2-hot)
            const uint4 lp = *(const uint4*)(lt + dp * 4);     // 4 i rows x 2 d (LDS b128)
            const h2_t av = u2h(at[dp]);                       // LDS b32 broadcast
            acc0.x = estep(rr.x, lp.x, av, acc0.x);
            acc0.y = estep(rr.y, lp.x, av, acc0.y);
            acc0.z = estep(rr.z, lp.x, av, acc0.z);
            acc0.w = estep(rr.w, lp.x, av, acc0.w);
            acc1.x = estep(rr.x, lp.y, av, acc1.x);
            acc1.y = estep(rr.y, lp.y, av, acc1.y);
            acc1.z = estep(rr.z, lp.y, av, acc1.z);
            acc1.w = estep(rr.w, lp.y, av, acc1.w);
            acc2.x = estep(rr.x, lp.z, av, acc2.x);
            acc2.y = estep(rr.y, lp.z, av, acc2.y);
            acc2.z = estep(rr.z, lp.z, av, acc2.z);
            acc2.w = estep(rr.w, lp.z, av, acc2.w);
            acc3.x = estep(rr.x, lp.w, av, acc3.x);
            acc3.y = estep(rr.y, lp.w, av, acc3.y);
            acc3.z = estep(rr.z, lp.w, av, acc3.z);
            acc3.w = estep(rr.w, lp.w, av, acc3.w);
        }
    }
    {
        float* myred = red + tid * 20;
        *(float4*)&myred[0]  = acc0;
        *(float4*)&myred[4]  = acc1;
        *(float4*)&myred[8]  = acc2;
        *(float4*)&myred[12] = acc3;
    }
    __syncthreads();

    // softmax: wave w owns row i0+w; lane l = j-quad
    {
        const int w = tid >> 6, l = tid & 63;
        float4 e0 = make_float4(0.f, 0.f, 0.f, 0.f);
        #pragma unroll
        for (int q4 = 0; q4 < 4; ++q4) {
            const float4 v = *(const float4*)&red[(q4 * 64 + l) * 20 + w * 4];
            e0.x += v.x; e0.y += v.y; e0.z += v.z; e0.w += v.w;
        }
        float4 ebs = make_float4(0.f, 0.f, 0.f, 0.f);
        #pragma unroll
        for (int seg = 0; seg < 4; ++seg) {
            const float4 v = *(const float4*)&eb[(hb * 4 + seg) * Kc + l * 4];
            ebs.x += v.x; ebs.y += v.y; ebs.z += v.z; ebs.w += v.w;
        }
        const float4 bv = *(const float4*)&bias[(h * Kc + i0 + w) * Kc + l * 4];
        e0.x += ebs.x + bv.x;
        e0.y += ebs.y + bv.y;
        e0.z += ebs.z + bv.z;
        e0.w += ebs.w + bv.w;

        float m = fmaxf(fmaxf(e0.x, e0.y), fmaxf(e0.z, e0.w));
        #pragma unroll
        for (int off = 1; off < 64; off <<= 1) m = fmaxf(m, __shfl_xor(m, off, 64));
        const float p0 = __expf(e0.x - m), p1 = __expf(e0.y - m);
        const float p2 = __expf(e0.z - m), p3 = __expf(e0.w - m);
        float s = p0 + p1 + p2 + p3;
        #pragma unroll
        for (int off = 1; off < 64; off <<= 1) s += __shfl_xor(s, off, 64);
        const float sc = 0.25f / s;     // fold mean over H
        uint2 pk;
        pk.x = f2bf(p0 * sc) | (f2bf(p1 * sc) << 16);
        pk.y = f2bf(p2 * sc) | (f2bf(p3 * sc) << 16);
        *(uint2*)&Pws[(hb * Kc + i0 + w) * Kc + l * 4] = pk;
    }

    // ---- arrival: last block of the (b,it) group does the PV ----
    __threadfence();                       // release our Pws writes (device scope)
    __syncthreads();                       // all threads fenced
    if (tid == 0) {
        const int old = atomicAdd(&cnt[b * 64 + it], 1);
        lastFlag = (old == 3);
    }
    __syncthreads();
    if (!lastFlag) return;
    __threadfence();                       // acquire the other producers' writes

    // P-bar = sum of 4 head planes (each already scaled 0.25)
    {
        const int r = tid >> 6, c = tid & 63;
        float4 s = make_float4(0.f, 0.f, 0.f, 0.f);
        #pragma unroll
        for (int hh = 0; hh < 4; ++hh) {
            const uint2 v = *(const uint2*)&Pws[((hh * 4 + b) * Kc + i0 + r) * Kc + c * 4];
            s.x += bf2f_lo(v.x); s.y += bf2f_hi(v.x);
            s.z += bf2f_lo(v.y); s.w += bf2f_hi(v.y);
        }
        *(float4*)&pbar4[r * Kc + c * 4] = s;
    }
    __syncthreads();

    // PV: out[i][d] = sum_j pbar[i][j] * x[b][j][d]
    const int jq = tid >> 5, dd4 = tid & 31;
    float4 o0 = make_float4(0.f, 0.f, 0.f, 0.f);
    float4 o1 = make_float4(0.f, 0.f, 0.f, 0.f);
    float4 o2 = make_float4(0.f, 0.f, 0.f, 0.f);
    float4 o3 = make_float4(0.f, 0.f, 0.f, 0.f);
    {
        const float* xb = x + (b * Kc) * Dc + dd4 * 4;
        #pragma unroll 4
        for (int jj = 0; jj < 32; ++jj) {
            const int j = jj * 8 + jq;
            const float4 xv = *(const float4*)(xb + j * Dc);   // global, L2-hot
            const float pv0 = pbar4[0 * Kc + j];
            const float pv1 = pbar4[1 * Kc + j];
            const float pv2 = pbar4[2 * Kc + j];
            const float pv3 = pbar4[3 * Kc + j];
            o0.x = fmaf(pv0, xv.x, o0.x); o0.y = fmaf(pv0, xv.y, o0.y);
            o0.z = fmaf(pv0, xv.z, o0.z); o0.w = fmaf(pv0, xv.w, o0.w);
            o1.x = fmaf(pv1, xv.x, o1.x); o1.y = fmaf(pv1, xv.y, o1.y);
            o1.z = fmaf(pv1, xv.z, o1.z); o1.w = fmaf(pv1, xv.w, o1.w);
            o2.x = fmaf(pv2, xv.x, o2.x); o2.y = fmaf(pv2, xv.y, o2.y);
            o2.z = fmaf(pv2, xv.z, o2.z); o2.w = fmaf(pv2, xv.w, o2.w);
            o3.x = fmaf(pv3, xv.x, o3.x); o3.y = fmaf(pv3, xv.y, o3.y);
            o3.z = fmaf(pv3, xv.z, o3.z); o3.w = fmaf(pv3, xv.w, o3.w);
        }
    }
    {
        float* myred = red + (jq * 32 + dd4) * 20;
        *(float4*)&myred[0]  = o0;
        *(float4*)&myred[4]  = o1;
        *(float4*)&myred[8]  = o2;
        *(float4*)&myred[12] = o3;
    }
    __syncthreads();
    if (tid < 128) {
        const int i_f = tid >> 5, dd_f = tid & 31;   // i_f 0..3, dd_f 0..31
        float4 s = make_float4(0.f, 0.f, 0.f, 0.f);
        #pragma unroll
        for (int q8 = 0; q8 < 8; ++q8) {
            const float4 v = *(const float4*)&red[(q8 * 32 + dd_f) * 20 + i_f * 4];
            s.x += v.x; s.y += v.y; s.z += v.z; s.w += v.w;
        }
        *(float4*)&out[(b * Kc + i0 + i_f) * Dc + dd_f * 4] = s;
    }
}

extern "C" void kernel_launch(void* const* d_in, const int* in_sizes, int n_in,
                              void* d_out, int out_size, void* d_ws, size_t ws_size,
                              hipStream_t stream) {
    const float* x     = (const float*)d_in[0];
    const float* W     = (const float*)d_in[1];
    const float* lin_b = (const float*)d_in[2];
    const float* a     = (const float*)d_in[3];
    const float* bias  = (const float*)d_in[4];
    float* out = (float*)d_out;

    unsigned int*   Lpp = (unsigned int*)d_ws;                // f16x2 [H][M][64]   (1 MB)
    unsigned int*   Rtp = Lpp + 4 * Mc * 64;                  // f16x2 [16][64][K]  (1 MB)
    float*          eb  = (float*)(Rtp + 16 * 64 * Kc);       // fp32  [16*4][K]    (64 KB)
    unsigned short* Pws = (unsigned short*)(eb + 16384);      // bf16  [16][K][K]   (2 MB)
    int*            cnt = (int*)(Pws + 16 * Kc * Kc);         // int   [256]

    k1<<<512, 256, 0, stream>>>(x, W, lin_b, a, Lpp, Rtp, eb, cnt);
    k2<<<1024, 256, 0, stream>>>(x, a, bias, Lpp, Rtp, eb, Pws, cnt, out);
}

// Round 10
// 27.528 us; speedup vs baseline: 5.0323x; 5.0323x over previous
//
#include <hip/hip_runtime.h>
#include <math.h>

// B=4, K=256, D=128, H=4, alpha=0.2
// leaky(s) = 0.6*s + 0.4*|s|  (exact for alpha=0.2)
// e_ij = [0.6*(a.Lp_i) cancels in softmax] + 0.6*(a.R_j) + sum_d (0.4 a_d)|Lp_id + R_jd| + bias_ij
// mean_h(P_h @ x) = (mean_h P_h) @ x  ->  k2 writes 0.25*P per head (bf16); k3 sums + single PV.
// Lp/Rt stored as packed-f16 d-pairs; k2 inner loop = pk_add + and(abs) + v_dot2_f32_f16.
constexpr int Kc = 256, Dc = 128, Mc = 1024;    // Mc = B*K

typedef _Float16 h2_t __attribute__((ext_vector_type(2)));
union U32H2 { unsigned int u; h2_t h; };
__device__ inline h2_t u2h(unsigned int u) { U32H2 x; x.u = u; return x.h; }
__device__ inline unsigned int h2u(h2_t h) { U32H2 x; x.h = h; return x.u; }
__device__ inline unsigned int packh(float a, float b) {
    h2_t h; h.x = (_Float16)a; h.y = (_Float16)b; return h2u(h);
}
__device__ inline unsigned int f2bf(float f) {      // fp32 -> bf16 bits (RNE)
    unsigned int u = __float_as_uint(f);
    return (u + 0x7FFFu + ((u >> 16) & 1u)) >> 16;
}
__device__ inline float bf2f_lo(unsigned int u) { return __uint_as_float(u << 16); }
__device__ inline float bf2f_hi(unsigned int u) { return __uint_as_float(u & 0xFFFF0000u); }

// acc += (0.4a_2d)|l_2d + r_2d| + (0.4a_2d+1)|l_2d+1 + r_2d+1|, f32 accumulate
__device__ inline float estep(unsigned int r, unsigned int l, h2_t av, float acc) {
    h2_t s = u2h(r) + u2h(l);                       // v_pk_add_f16
    unsigned int t = h2u(s) & 0x7FFF7FFFu;          // packed abs
#if __has_builtin(__builtin_amdgcn_fdot2)
    return __builtin_amdgcn_fdot2(u2h(t), av, acc, false);   // v_dot2_f32_f16
#else
    h2_t th = u2h(t);
    return fmaf((float)th.x, (float)av.x, fmaf((float)th.y, (float)av.y, acc));
#endif
}

// ---------------------------------------------------------------------------
// K1 (512 blocks, 256 thr): 32x64-tile fp32 GEMM, 2x4 reg block.
//   bid <  256 : Lpp[h][m][dp] = packed-f16 pair of (x@W_src + lin_b)
//   bid >= 256 : Rtp[hb][dp][j] = packed-f16 pair of (x@W_dst)^T
//                + eb[(hb*4+dt)][j] = 1.5 * sum_{d in 32-slice} 0.4*a_d*R_jd (fp32)
// ---------------------------------------------------------------------------
__global__ __launch_bounds__(256) void k1(const float* __restrict__ x,
                                          const float* __restrict__ W,
                                          const float* __restrict__ lin_b,
                                          const float* __restrict__ a,
                                          unsigned int* __restrict__ Lpp,
                                          unsigned int* __restrict__ Rtp,
                                          float* __restrict__ eb) {
    __shared__ float As[128][32];   // [k][m-role] 16 KB
    __shared__ float Bs[128][64];   // [k][n-role] 32 KB
    __shared__ float red[4][16][4];

    const int tid = threadIdx.x;
    const int bid = blockIdx.x;
    const int tx = tid & 15, ty = tid >> 4;   // ty 0..15
    const bool isL = (bid < 256);

    int h, b, m0, n0, dt;
    if (isL) {
        const int nt = bid & 1, mt = (bid >> 1) & 31;
        h = (bid >> 6) & 3;
        m0 = mt * 32; n0 = nt * 64; b = 0; dt = 0;
        {
            const int m_l = tid & 31, kq = tid >> 5;
            #pragma unroll
            for (int c = 0; c < 4; ++c) {
                const int k0 = kq * 16 + c * 4;
                const float4 v = *(const float4*)&x[(m0 + m_l) * Dc + k0];
                As[k0 + 0][m_l] = v.x; As[k0 + 1][m_l] = v.y;
                As[k0 + 2][m_l] = v.z; As[k0 + 3][m_l] = v.w;
            }
        }
        {
            const int n_l = tid & 63, kq = tid >> 6;
            const float* Wb = W + (h * 2) * Dc * Dc;
            #pragma unroll
            for (int kk = 0; kk < 32; ++kk) {
                const int k = kq * 32 + kk;
                Bs[k][n_l] = Wb[k * Dc + n0 + n_l];
            }
        }
    } else {
        const int r_ = bid - 256;
        const int jt = r_ & 3;
        dt = (r_ >> 2) & 3;
        b  = (r_ >> 4) & 3;
        h  = (r_ >> 6) & 3;
        m0 = dt * 32;          // m-role = d
        n0 = jt * 64;          // n-role = j
        {
            const int d_l = tid & 31, kq = tid >> 5;
            const float* Wb = W + ((h * 2 + 1) * Dc) * Dc;
            #pragma unroll
            for (int kk = 0; kk < 16; ++kk) {
                const int k = kq * 16 + kk;
                As[k][d_l] = Wb[k * Dc + m0 + d_l];
            }
        }
        {
            const int j_l = tid & 63, kq = tid >> 6;
            #pragma unroll
            for (int c = 0; c < 8; ++c) {
                const int k0 = kq * 32 + c * 4;
                const float4 v = *(const float4*)&x[(b * Kc + n0 + j_l) * Dc + k0];
                Bs[k0 + 0][j_l] = v.x; Bs[k0 + 1][j_l] = v.y;
                Bs[k0 + 2][j_l] = v.z; Bs[k0 + 3][j_l] = v.w;
            }
        }
    }
    __syncthreads();

    float acc[2][4];
    #pragma unroll
    for (int r = 0; r < 2; ++r)
        #pragma unroll
        for (int c = 0; c < 4; ++c) acc[r][c] = 0.f;

    #pragma unroll 16
    for (int k = 0; k < 128; ++k) {
        const float2 xa = *(const float2*)&As[k][ty * 2];
        const float4 wb = *(const float4*)&Bs[k][tx * 4];
        acc[0][0] = fmaf(xa.x, wb.x, acc[0][0]);
        acc[0][1] = fmaf(xa.x, wb.y, acc[0][1]);
        acc[0][2] = fmaf(xa.x, wb.z, acc[0][2]);
        acc[0][3] = fmaf(xa.x, wb.w, acc[0][3]);
        acc[1][0] = fmaf(xa.y, wb.x, acc[1][0]);
        acc[1][1] = fmaf(xa.y, wb.y, acc[1][1]);
        acc[1][2] = fmaf(xa.y, wb.z, acc[1][2]);
        acc[1][3] = fmaf(xa.y, wb.w, acc[1][3]);
    }

    if (isL) {
        const float4 lv = *(const float4*)&lin_b[h * Dc + n0 + tx * 4];
        #pragma unroll
        for (int r = 0; r < 2; ++r) {
            uint2 pk;
            pk.x = packh(acc[r][0] + lv.x, acc[r][1] + lv.y);
            pk.y = packh(acc[r][2] + lv.z, acc[r][3] + lv.w);
            *(uint2*)&Lpp[(h * Mc + m0 + ty * 2 + r) * 64 + (n0 >> 1) + tx * 2] = pk;
        }
    } else {
        {
            uint4 pk;
            pk.x = packh(acc[0][0], acc[1][0]);
            pk.y = packh(acc[0][1], acc[1][1]);
            pk.z = packh(acc[0][2], acc[1][2]);
            pk.w = packh(acc[0][3], acc[1][3]);
            *(uint4*)&Rtp[((h * 4 + b) * 64 + (m0 >> 1) + ty) * Kc + n0 + tx * 4] = pk;
        }
        const float2 av = *(const float2*)&a[h * Dc + m0 + ty * 2];
        float p0 = 0.4f * (av.x * acc[0][0] + av.y * acc[1][0]);
        float p1 = 0.4f * (av.x * acc[0][1] + av.y * acc[1][1]);
        float p2 = 0.4f * (av.x * acc[0][2] + av.y * acc[1][2]);
        float p3 = 0.4f * (av.x * acc[0][3] + av.y * acc[1][3]);
        p0 += __shfl_xor(p0, 16, 64); p0 += __shfl_xor(p0, 32, 64);
        p1 += __shfl_xor(p1, 16, 64); p1 += __shfl_xor(p1, 32, 64);
        p2 += __shfl_xor(p2, 16, 64); p2 += __shfl_xor(p2, 32, 64);
        p3 += __shfl_xor(p3, 16, 64); p3 += __shfl_xor(p3, 32, 64);
        if (((tid >> 4) & 3) == 0) {
            const int w = tid >> 6;
            red[w][tx][0] = p0; red[w][tx][1] = p1;
            red[w][tx][2] = p2; red[w][tx][3] = p3;
        }
        __syncthreads();
        if (tid < 64) {
            const int txl = tid >> 2, c = tid & 3;
            const float v = red[0][txl][c] + red[1][txl][c] + red[2][txl][c] + red[3][txl][c];
            eb[((h * 4 + b) * 4 + dt) * Kc + n0 + tid] = 1.5f * v;
        }
    }
}

// ---------------------------------------------------------------------------
// K2 (512 blocks = (hb, 32 i-tiles of 8 rows), 256 thr, 2 blocks/CU,
// XCD-pinned): thread (dq=tid>>6, j4=tid&63) owns acc[8i][4j] over a 32-d
// slice (16 packed pairs). Rt plane read once per block (32 MB L2 total,
// half of R8). Padded-LDS dq-reduce -> 2-rows-per-wave shuffle softmax ->
// 0.25*P (bf16) to Pws.
// ---------------------------------------------------------------------------
#define E4(ACC, LPV)                               \
    ACC.x = estep(rr.x, LPV, av, ACC.x);           \
    ACC.y = estep(rr.y, LPV, av, ACC.y);           \
    ACC.z = estep(rr.z, LPV, av, ACC.z);           \
    ACC.w = estep(rr.w, LPV, av, ACC.w);

__global__ __launch_bounds__(256) void k2(const float* __restrict__ a,
                                          const float* __restrict__ bias,
                                          const unsigned int* __restrict__ Lpp,
                                          const unsigned int* __restrict__ Rtp,
                                          const float* __restrict__ eb,
                                          unsigned short* __restrict__ Pws) {
    __shared__ float red[256 * 36];        // 36 KB dq-reduce scratch (32 floats + 4 pad)
    __shared__ unsigned int lpT2[64 * 8];  // [dp][i] 2 KB packed-f16 Lp (8 rows)
    __shared__ unsigned int aa2s[64];      // packed-f16 0.4*a pairs

    const int tid = threadIdx.x;
    const int L = blockIdx.x;
    // XCD-pin: consecutive blockIdx round-robin across XCDs (heuristic).
    const int xcd = L & 7, q = L >> 3;       // q 0..63
    const int hb = (xcd << 1) | (q & 1);     // 2 planes per XCD
    const int it = q >> 1;                   // 0..31
    const int h = hb >> 2, b = hb & 3;
    const int i0 = it * 8;

    {   // stage lpT2[dp][i] for 8 rows: thread -> (dp = tid>>2, iPair = (tid&3)*2)
        const int dp = tid >> 2, ip = (tid & 3) * 2;
        uint2 v;
        v.x = Lpp[(h * Mc + b * Kc + i0 + ip + 0) * 64 + dp];
        v.y = Lpp[(h * Mc + b * Kc + i0 + ip + 1) * 64 + dp];
        *(uint2*)&lpT2[dp * 8 + ip] = v;
    }
    if (tid < 64) aa2s[tid] = packh(0.4f * a[h * Dc + 2 * tid], 0.4f * a[h * Dc + 2 * tid + 1]);
    __syncthreads();

    const int dq = tid >> 6, j4 = tid & 63;
    float4 a0 = make_float4(0.f, 0.f, 0.f, 0.f), a1 = a0, a2 = a0, a3 = a0;
    float4 a4 = a0, a5 = a0, a6 = a0, a7 = a0;
    {
        const unsigned int* rb = Rtp + (hb * 64 + dq * 16) * Kc + j4 * 4;
        const unsigned int* lt = lpT2 + dq * 16 * 8;
        const unsigned int* at = aa2s + dq * 16;
        #pragma unroll
        for (int dp = 0; dp < 16; ++dp) {
            const uint4 rr  = *(const uint4*)(rb + dp * Kc);     // 4 j cols x 2 d (global, L2-hot)
            const uint4 lpA = *(const uint4*)(lt + dp * 8);      // i rows 0..3 x 2 d (LDS b128)
            const uint4 lpB = *(const uint4*)(lt + dp * 8 + 4);  // i rows 4..7
            const h2_t av = u2h(at[dp]);                         // LDS b32 broadcast
            E4(a0, lpA.x); E4(a1, lpA.y); E4(a2, lpA.z); E4(a3, lpA.w);
            E4(a4, lpB.x); E4(a5, lpB.y); E4(a6, lpB.z); E4(a7, lpB.w);
        }
    }
    {
        float* myred = red + tid * 36;
        *(float4*)&myred[0]  = a0;  *(float4*)&myred[4]  = a1;
        *(float4*)&myred[8]  = a2;  *(float4*)&myred[12] = a3;
        *(float4*)&myred[16] = a4;  *(float4*)&myred[20] = a5;
        *(float4*)&myred[24] = a6;  *(float4*)&myred[28] = a7;
    }
    __syncthreads();

    // softmax: wave w owns rows r0=2w, r1=2w+1; lane l = j-quad
    {
        const int w = tid >> 6, l = tid & 63;
        const int r0 = 2 * w, r1 = 2 * w + 1;
        float4 e0 = make_float4(0.f, 0.f, 0.f, 0.f);
        float4 e1 = make_float4(0.f, 0.f, 0.f, 0.f);
        #pragma unroll
        for (int q4 = 0; q4 < 4; ++q4) {
            const float* rp = red + (q4 * 64 + l) * 36;
            const float4 v0 = *(const float4*)&rp[r0 * 4];
            const float4 v1 = *(const float4*)&rp[r1 * 4];
            e0.x += v0.x; e0.y += v0.y; e0.z += v0.z; e0.w += v0.w;
            e1.x += v1.x; e1.y += v1.y; e1.z += v1.z; e1.w += v1.w;
        }
        float4 ebs = make_float4(0.f, 0.f, 0.f, 0.f);
        #pragma unroll
        for (int seg = 0; seg < 4; ++seg) {
            const float4 v = *(const float4*)&eb[(hb * 4 + seg) * Kc + l * 4];
            ebs.x += v.x; ebs.y += v.y; ebs.z += v.z; ebs.w += v.w;
        }
        const float4 bv0 = *(const float4*)&bias[(h * Kc + i0 + r0) * Kc + l * 4];
        const float4 bv1 = *(const float4*)&bias[(h * Kc + i0 + r1) * Kc + l * 4];
        e0.x += ebs.x + bv0.x; e0.y += ebs.y + bv0.y;
        e0.z += ebs.z + bv0.z; e0.w += ebs.w + bv0.w;
        e1.x += ebs.x + bv1.x; e1.y += ebs.y + bv1.y;
        e1.z += ebs.z + bv1.z; e1.w += ebs.w + bv1.w;

        {
            float m = fmaxf(fmaxf(e0.x, e0.y), fmaxf(e0.z, e0.w));
            #pragma unroll
            for (int off = 1; off < 64; off <<= 1) m = fmaxf(m, __shfl_xor(m, off, 64));
            const float p0 = __expf(e0.x - m), p1 = __expf(e0.y - m);
            const float p2 = __expf(e0.z - m), p3 = __expf(e0.w - m);
            float s = p0 + p1 + p2 + p3;
            #pragma unroll
            for (int off = 1; off < 64; off <<= 1) s += __shfl_xor(s, off, 64);
            const float sc = 0.25f / s;
            uint2 pk;
            pk.x = f2bf(p0 * sc) | (f2bf(p1 * sc) << 16);
            pk.y = f2bf(p2 * sc) | (f2bf(p3 * sc) << 16);
            *(uint2*)&Pws[(hb * Kc + i0 + r0) * Kc + l * 4] = pk;
        }
        {
            float m = fmaxf(fmaxf(e1.x, e1.y), fmaxf(e1.z, e1.w));
            #pragma unroll
            for (int off = 1; off < 64; off <<= 1) m = fmaxf(m, __shfl_xor(m, off, 64));
            const float p0 = __expf(e1.x - m), p1 = __expf(e1.y - m);
            const float p2 = __expf(e1.z - m), p3 = __expf(e1.w - m);
            float s = p0 + p1 + p2 + p3;
            #pragma unroll
            for (int off = 1; off < 64; off <<= 1) s += __shfl_xor(s, off, 64);
            const float sc = 0.25f / s;
            uint2 pk;
            pk.x = f2bf(p0 * sc) | (f2bf(p1 * sc) << 16);
            pk.y = f2bf(p2 * sc) | (f2bf(p3 * sc) << 16);
            *(uint2*)&Pws[(hb * Kc + i0 + r1) * Kc + l * 4] = pk;
        }
    }
}

// ---------------------------------------------------------------------------
// K3 (512 blocks = (b, 128 i-tiles of 2 rows), 256 thr): P-bar = sum_h Pws(bf16),
// then single PV: out[i][d] = sum_j Pbar[i][j] * x[b][j][d].
// ---------------------------------------------------------------------------
__global__ __launch_bounds__(256) void k3(const float* __restrict__ x,
                                          const unsigned short* __restrict__ Pws,
                                          float* __restrict__ out) {
    __shared__ float pbar[2 * Kc];    // 2 KB
    __shared__ float red[256 * 12];   // 12 KB jq-reduce scratch

    const int tid = threadIdx.x;
    const int bid = blockIdx.x;
    const int b = bid >> 7, it = bid & 127;
    const int i0 = it * 2;

    if (tid < 128) {
        const int r = tid >> 6, c = tid & 63;
        float4 s = make_float4(0.f, 0.f, 0.f, 0.f);
        #pragma unroll
        for (int h = 0; h < 4; ++h) {
            const uint2 v = *(const uint2*)&Pws[((h * 4 + b) * Kc + i0 + r) * Kc + c * 4];
            s.x += bf2f_lo(v.x); s.y += bf2f_hi(v.x);
            s.z += bf2f_lo(v.y); s.w += bf2f_hi(v.y);
        }
        *(float4*)&pbar[r * Kc + c * 4] = s;
    }
    __syncthreads();

    const int jq = tid >> 5, dd4 = tid & 31;
    float4 o0 = make_float4(0.f, 0.f, 0.f, 0.f);
    float4 o1 = make_float4(0.f, 0.f, 0.f, 0.f);
    {
        const float* xb = x + (b * Kc) * Dc + dd4 * 4;
        #pragma unroll 4
        for (int jj = 0; jj < 32; ++jj) {
            const int j = jj * 8 + jq;
            const float4 xv = *(const float4*)(xb + j * Dc);   // global, L2-hot
            const float pv0 = pbar[j];                          // LDS broadcast
            const float pv1 = pbar[Kc + j];
            o0.x = fmaf(pv0, xv.x, o0.x); o0.y = fmaf(pv0, xv.y, o0.y);
            o0.z = fmaf(pv0, xv.z, o0.z); o0.w = fmaf(pv0, xv.w, o0.w);
            o1.x = fmaf(pv1, xv.x, o1.x); o1.y = fmaf(pv1, xv.y, o1.y);
            o1.z = fmaf(pv1, xv.z, o1.z); o1.w = fmaf(pv1, xv.w, o1.w);
        }
    }
    {
        float* myred = red + (jq * 32 + dd4) * 12;
        *(float4*)&myred[0] = o0;
        *(float4*)&myred[4] = o1;
    }
    __syncthreads();
    if (tid < 64) {
        const int i_f = tid >> 5, dd_f = tid & 31;
        float4 s = make_float4(0.f, 0.f, 0.f, 0.f);
        #pragma unroll
        for (int q = 0; q < 8; ++q) {
            const float4 v = *(const float4*)&red[(q * 32 + dd_f) * 12 + i_f * 4];
            s.x += v.x; s.y += v.y; s.z += v.z; s.w += v.w;
        }
        *(float4*)&out[(b * Kc + i0 + i_f) * Dc + dd_f * 4] = s;
    }
}

extern "C" void kernel_launch(void* const* d_in, const int* in_sizes, int n_in,
                              void* d_out, int out_size, void* d_ws, size_t ws_size,
                              hipStream_t stream) {
    const float* x     = (const float*)d_in[0];
    const float* W     = (const float*)d_in[1];
    const float* lin_b = (const float*)d_in[2];
    const float* a     = (const float*)d_in[3];
    const float* bias  = (const float*)d_in[4];
    float* out = (float*)d_out;

    unsigned int*   Lpp = (unsigned int*)d_ws;                // f16x2 [H][M][64]   (1 MB)
    unsigned int*   Rtp = Lpp + 4 * Mc * 64;                  // f16x2 [16][64][K]  (1 MB)
    float*          eb  = (float*)(Rtp + 16 * 64 * Kc);       // fp32  [16*4][K]    (64 KB)
    unsigned short* Pws = (unsigned short*)(eb + 16384);      // bf16  [16][K][K]   (2 MB)

    k1<<<512, 256, 0, stream>>>(x, W, lin_b, a, Lpp, Rtp, eb);
    k2<<<512, 256, 0, stream>>>(a, bias, Lpp, Rtp, eb, Pws);
    k3<<<512, 256, 0, stream>>>(x, Pws, out);
}

// Round 11
// 26.428 us; speedup vs baseline: 5.2417x; 1.0416x over previous
//
#include <hip/hip_runtime.h>
#include <math.h>

// B=4, K=256, D=128, H=4, alpha=0.2
// leaky(s) = 0.6*s + 0.4*|s|  (exact for alpha=0.2)
// e_ij = [0.6*(a.Lp_i) cancels in softmax] + 0.6*(a.R_j) + sum_d (0.4 a_d)|Lp_id + R_jd| + bias_ij
// mean_h(P_h @ x) = (mean_h P_h) @ x.
// Fused k2: each block owns (b, 2-row i-tile) for ALL 4 heads -> P-bar in fp32 LDS,
// single PV, direct out write. No Pws plane, no k3 dispatch, no device fences.
constexpr int Kc = 256, Dc = 128, Mc = 1024;    // Mc = B*K

typedef _Float16 h2_t __attribute__((ext_vector_type(2)));
union U32H2 { unsigned int u; h2_t h; };
__device__ inline h2_t u2h(unsigned int u) { U32H2 x; x.u = u; return x.h; }
__device__ inline unsigned int h2u(h2_t h) { U32H2 x; x.h = h; return x.u; }
__device__ inline unsigned int packh(float a, float b) {
    h2_t h; h.x = (_Float16)a; h.y = (_Float16)b; return h2u(h);
}

// acc += (0.4a_2d)|l_2d + r_2d| + (0.4a_2d+1)|l_2d+1 + r_2d+1|, f32 accumulate
__device__ inline float estep(unsigned int r, unsigned int l, h2_t av, float acc) {
    h2_t s = u2h(r) + u2h(l);                       // v_pk_add_f16
    unsigned int t = h2u(s) & 0x7FFF7FFFu;          // packed abs
#if __has_builtin(__builtin_amdgcn_fdot2)
    return __builtin_amdgcn_fdot2(u2h(t), av, acc, false);   // v_dot2_f32_f16
#else
    h2_t th = u2h(t);
    return fmaf((float)th.x, (float)av.x, fmaf((float)th.y, (float)av.y, acc));
#endif
}

// ---------------------------------------------------------------------------
// K1 (512 blocks, 256 thr): 32x64-tile fp32 GEMM, 2x4 reg block.  (unchanged)
//   bid <  256 : Lpp[h][m][dp] = packed-f16 pair of (x@W_src + lin_b)
//   bid >= 256 : Rtp[hb][dp][j] = packed-f16 pair of (x@W_dst)^T
//                + eb[(hb*4+dt)][j] = 1.5 * sum_{d in 32-slice} 0.4*a_d*R_jd (fp32)
// ---------------------------------------------------------------------------
__global__ __launch_bounds__(256) void k1(const float* __restrict__ x,
                                          const float* __restrict__ W,
                                          const float* __restrict__ lin_b,
                                          const float* __restrict__ a,
                                          unsigned int* __restrict__ Lpp,
                                          unsigned int* __restrict__ Rtp,
                                          float* __restrict__ eb) {
    __shared__ float As[128][32];   // [k][m-role] 16 KB
    __shared__ float Bs[128][64];   // [k][n-role] 32 KB
    __shared__ float red[4][16][4];

    const int tid = threadIdx.x;
    const int bid = blockIdx.x;
    const int tx = tid & 15, ty = tid >> 4;   // ty 0..15
    const bool isL = (bid < 256);

    int h, b, m0, n0, dt;
    if (isL) {
        const int nt = bid & 1, mt = (bid >> 1) & 31;
        h = (bid >> 6) & 3;
        m0 = mt * 32; n0 = nt * 64; b = 0; dt = 0;
        {
            const int m_l = tid & 31, kq = tid >> 5;
            #pragma unroll
            for (int c = 0; c < 4; ++c) {
                const int k0 = kq * 16 + c * 4;
                const float4 v = *(const float4*)&x[(m0 + m_l) * Dc + k0];
                As[k0 + 0][m_l] = v.x; As[k0 + 1][m_l] = v.y;
                As[k0 + 2][m_l] = v.z; As[k0 + 3][m_l] = v.w;
            }
        }
        {
            const int n_l = tid & 63, kq = tid >> 6;
            const float* Wb = W + (h * 2) * Dc * Dc;
            #pragma unroll
            for (int kk = 0; kk < 32; ++kk) {
                const int k = kq * 32 + kk;
                Bs[k][n_l] = Wb[k * Dc + n0 + n_l];
            }
        }
    } else {
        const int r_ = bid - 256;
        const int jt = r_ & 3;
        dt = (r_ >> 2) & 3;
        b  = (r_ >> 4) & 3;
        h  = (r_ >> 6) & 3;
        m0 = dt * 32;          // m-role = d
        n0 = jt * 64;          // n-role = j
        {
            const int d_l = tid & 31, kq = tid >> 5;
            const float* Wb = W + ((h * 2 + 1) * Dc) * Dc;
            #pragma unroll
            for (int kk = 0; kk < 16; ++kk) {
                const int k = kq * 16 + kk;
                As[k][d_l] = Wb[k * Dc + m0 + d_l];
            }
        }
        {
            const int j_l = tid & 63, kq = tid >> 6;
            #pragma unroll
            for (int c = 0; c < 8; ++c) {
                const int k0 = kq * 32 + c * 4;
                const float4 v = *(const float4*)&x[(b * Kc + n0 + j_l) * Dc + k0];
                Bs[k0 + 0][j_l] = v.x; Bs[k0 + 1][j_l] = v.y;
                Bs[k0 + 2][j_l] = v.z; Bs[k0 + 3][j_l] = v.w;
            }
        }
    }
    __syncthreads();

    float acc[2][4];
    #pragma unroll
    for (int r = 0; r < 2; ++r)
        #pragma unroll
        for (int c = 0; c < 4; ++c) acc[r][c] = 0.f;

    #pragma unroll 16
    for (int k = 0; k < 128; ++k) {
        const float2 xa = *(const float2*)&As[k][ty * 2];
        const float4 wb = *(const float4*)&Bs[k][tx * 4];
        acc[0][0] = fmaf(xa.x, wb.x, acc[0][0]);
        acc[0][1] = fmaf(xa.x, wb.y, acc[0][1]);
        acc[0][2] = fmaf(xa.x, wb.z, acc[0][2]);
        acc[0][3] = fmaf(xa.x, wb.w, acc[0][3]);
        acc[1][0] = fmaf(xa.y, wb.x, acc[1][0]);
        acc[1][1] = fmaf(xa.y, wb.y, acc[1][1]);
        acc[1][2] = fmaf(xa.y, wb.z, acc[1][2]);
        acc[1][3] = fmaf(xa.y, wb.w, acc[1][3]);
    }

    if (isL) {
        const float4 lv = *(const float4*)&lin_b[h * Dc + n0 + tx * 4];
        #pragma unroll
        for (int r = 0; r < 2; ++r) {
            uint2 pk;
            pk.x = packh(acc[r][0] + lv.x, acc[r][1] + lv.y);
            pk.y = packh(acc[r][2] + lv.z, acc[r][3] + lv.w);
            *(uint2*)&Lpp[(h * Mc + m0 + ty * 2 + r) * 64 + (n0 >> 1) + tx * 2] = pk;
        }
    } else {
        {
            uint4 pk;
            pk.x = packh(acc[0][0], acc[1][0]);
            pk.y = packh(acc[0][1], acc[1][1]);
            pk.z = packh(acc[0][2], acc[1][2]);
            pk.w = packh(acc[0][3], acc[1][3]);
            *(uint4*)&Rtp[((h * 4 + b) * 64 + (m0 >> 1) + ty) * Kc + n0 + tx * 4] = pk;
        }
        const float2 av = *(const float2*)&a[h * Dc + m0 + ty * 2];
        float p0 = 0.4f * (av.x * acc[0][0] + av.y * acc[1][0]);
        float p1 = 0.4f * (av.x * acc[0][1] + av.y * acc[1][1]);
        float p2 = 0.4f * (av.x * acc[0][2] + av.y * acc[1][2]);
        float p3 = 0.4f * (av.x * acc[0][3] + av.y * acc[1][3]);
        p0 += __shfl_xor(p0, 16, 64); p0 += __shfl_xor(p0, 32, 64);
        p1 += __shfl_xor(p1, 16, 64); p1 += __shfl_xor(p1, 32, 64);
        p2 += __shfl_xor(p2, 16, 64); p2 += __shfl_xor(p2, 32, 64);
        p3 += __shfl_xor(p3, 16, 64); p3 += __shfl_xor(p3, 32, 64);
        if (((tid >> 4) & 3) == 0) {
            const int w = tid >> 6;
            red[w][tx][0] = p0; red[w][tx][1] = p1;
            red[w][tx][2] = p2; red[w][tx][3] = p3;
        }
        __syncthreads();
        if (tid < 64) {
            const int txl = tid >> 2, c = tid & 3;
            const float v = red[0][txl][c] + red[1][txl][c] + red[2][txl][c] + red[3][txl][c];
            eb[((h * 4 + b) * 4 + dt) * Kc + n0 + tid] = 1.5f * v;
        }
    }
}

// ---------------------------------------------------------------------------
// K2 fused (512 blocks = (b, 128 i-tiles of 2 rows), 256 thr, 2 blk/CU,
// b pinned per XCD): per head h: e-phase (thread (dq,j4) owns acc[2i][4j]
// over a 32-d slice, Rt from global/L2) -> padded-LDS dq-reduce -> wave
// softmax (waves 0,1) -> accumulate P-bar (fp32 LDS).  Then single PV with
// x from global/L2, jq-reduce, write final out.
// ---------------------------------------------------------------------------
#define E4(ACC, LPV)                               \
    ACC.x = estep(rr.x, LPV, av, ACC.x);           \
    ACC.y = estep(rr.y, LPV, av, ACC.y);           \
    ACC.z = estep(rr.z, LPV, av, ACC.z);           \
    ACC.w = estep(rr.w, LPV, av, ACC.w);

__global__ __launch_bounds__(256) void k2(const float* __restrict__ x,
                                          const float* __restrict__ a,
                                          const float* __restrict__ bias,
                                          const unsigned int* __restrict__ Lpp,
                                          const unsigned int* __restrict__ Rtp,
                                          const float* __restrict__ eb,
                                          float* __restrict__ out) {
    __shared__ float red[256 * 12];          // 12 KB reduce scratch (e-phase, then PV)
    __shared__ unsigned int lpT2[4 * 64 * 2]; // [h][dp][i] 2 KB packed-f16 Lp
    __shared__ unsigned int aa2s[4 * 64];     // [h][dp] packed-f16 0.4*a pairs 1 KB
    __shared__ float plbar[2 * Kc];           // fp32 P-bar accumulator 2 KB

    const int tid = threadIdx.x;
    const int L = blockIdx.x;
    // XCD-pin: L&7 -> XCD; b = xcd>>1 (2 XCDs per b); it from remaining bits.
    const int xcd = L & 7;
    const int b = xcd >> 1;
    const int it = ((L >> 3) << 1) | (xcd & 1);   // 0..127
    const int i0 = it * 2;

    {   // stage lpT2[h][dp][i]: thread -> (h = tid>>6, dp = tid&63), both i rows
        const int h = tid >> 6, dp = tid & 63;
        uint2 v;
        v.x = Lpp[(h * Mc + b * Kc + i0 + 0) * 64 + dp];
        v.y = Lpp[(h * Mc + b * Kc + i0 + 1) * 64 + dp];
        *(uint2*)&lpT2[(h * 64 + dp) * 2] = v;
        aa2s[tid] = packh(0.4f * a[h * Dc + 2 * dp], 0.4f * a[h * Dc + 2 * dp + 1]);
    }
    if (tid < 128) ((float4*)plbar)[tid] = make_float4(0.f, 0.f, 0.f, 0.f);
    __syncthreads();

    const int dq = tid >> 6, j4 = tid & 63;
    const int w = tid >> 6, l = tid & 63;

    #pragma unroll 1
    for (int h = 0; h < 4; ++h) {
        const int hb = h * 4 + b;
        float4 acc0 = make_float4(0.f, 0.f, 0.f, 0.f);
        float4 acc1 = make_float4(0.f, 0.f, 0.f, 0.f);
        {
            const unsigned int* rb = Rtp + (hb * 64 + dq * 16) * Kc + j4 * 4;
            const unsigned int* lt = lpT2 + (h * 64 + dq * 16) * 2;
            const unsigned int* at = aa2s + h * 64 + dq * 16;
            #pragma unroll
            for (int dp = 0; dp < 16; ++dp) {
                const uint4 rr = *(const uint4*)(rb + dp * Kc);    // 4 j x 2 d (global, L2-hot)
                const uint2 lp2 = *(const uint2*)(lt + dp * 2);    // 2 i x 2 d (LDS b64)
                const h2_t av = u2h(at[dp]);                       // LDS b32 broadcast
                E4(acc0, lp2.x);
                E4(acc1, lp2.y);
            }
        }
        {
            float* myred = red + tid * 12;
            *(float4*)&myred[0] = acc0;
            *(float4*)&myred[4] = acc1;
        }
        __syncthreads();

        // softmax: wave w (0,1) owns row i0+w; lane l = j-quad
        if (w < 2) {
            float4 e0 = make_float4(0.f, 0.f, 0.f, 0.f);
            #pragma unroll
            for (int q4 = 0; q4 < 4; ++q4) {
                const float4 v = *(const float4*)&red[(q4 * 64 + l) * 12 + w * 4];
                e0.x += v.x; e0.y += v.y; e0.z += v.z; e0.w += v.w;
            }
            float4 ebs = make_float4(0.f, 0.f, 0.f, 0.f);
            #pragma unroll
            for (int seg = 0; seg < 4; ++seg) {
                const float4 v = *(const float4*)&eb[(hb * 4 + seg) * Kc + l * 4];
                ebs.x += v.x; ebs.y += v.y; ebs.z += v.z; ebs.w += v.w;
            }
            const float4 bv = *(const float4*)&bias[(h * Kc + i0 + w) * Kc + l * 4];
            e0.x += ebs.x + bv.x;
            e0.y += ebs.y + bv.y;
            e0.z += ebs.z + bv.z;
            e0.w += ebs.w + bv.w;

            float m = fmaxf(fmaxf(e0.x, e0.y), fmaxf(e0.z, e0.w));
            #pragma unroll
            for (int off = 1; off < 64; off <<= 1) m = fmaxf(m, __shfl_xor(m, off, 64));
            const float p0 = __expf(e0.x - m), p1 = __expf(e0.y - m);
            const float p2 = __expf(e0.z - m), p3 = __expf(e0.w - m);
            float s = p0 + p1 + p2 + p3;
            #pragma unroll
            for (int off = 1; off < 64; off <<= 1) s += __shfl_xor(s, off, 64);
            const float sc = 0.25f / s;     // fold mean over H
            float4 cur = *(float4*)&plbar[w * Kc + l * 4];
            cur.x = fmaf(p0, sc, cur.x);
            cur.y = fmaf(p1, sc, cur.y);
            cur.z = fmaf(p2, sc, cur.z);
            cur.w = fmaf(p3, sc, cur.w);
            *(float4*)&plbar[w * Kc + l * 4] = cur;
        }
        __syncthreads();
    }

    // ---- single PV with P-bar: out[i][d] = sum_j plbar[i][j] * x[b][j][d] ----
    const int jq = tid >> 5, dd4 = tid & 31;
    float4 o0 = make_float4(0.f, 0.f, 0.f, 0.f);
    float4 o1 = make_float4(0.f, 0.f, 0.f, 0.f);
    {
        const float* xb = x + (b * Kc) * Dc + dd4 * 4;
        #pragma unroll 4
        for (int jj = 0; jj < 32; ++jj) {
            const int j = jj * 8 + jq;
            const float4 xv = *(const float4*)(xb + j * Dc);   // global, L2-hot
            const float pv0 = plbar[j];                         // LDS broadcast
            const float pv1 = plbar[Kc + j];
            o0.x = fmaf(pv0, xv.x, o0.x); o0.y = fmaf(pv0, xv.y, o0.y);
            o0.z = fmaf(pv0, xv.z, o0.z); o0.w = fmaf(pv0, xv.w, o0.w);
            o1.x = fmaf(pv1, xv.x, o1.x); o1.y = fmaf(pv1, xv.y, o1.y);
            o1.z = fmaf(pv1, xv.z, o1.z); o1.w = fmaf(pv1, xv.w, o1.w);
        }
    }
    {
        float* myred = red + (jq * 32 + dd4) * 12;
        *(float4*)&myred[0] = o0;
        *(float4*)&myred[4] = o1;
    }
    __syncthreads();
    if (tid < 64) {
        const int i_f = tid >> 5, dd_f = tid & 31;
        float4 s = make_float4(0.f, 0.f, 0.f, 0.f);
        #pragma unroll
        for (int q = 0; q < 8; ++q) {
            const float4 v = *(const float4*)&red[(q * 32 + dd_f) * 12 + i_f * 4];
            s.x += v.x; s.y += v.y; s.z += v.z; s.w += v.w;
        }
        *(float4*)&out[(b * Kc + i0 + i_f) * Dc + dd_f * 4] = s;
    }
}

extern "C" void kernel_launch(void* const* d_in, const int* in_sizes, int n_in,
                              void* d_out, int out_size, void* d_ws, size_t ws_size,
                              hipStream_t stream) {
    const float* x     = (const float*)d_in[0];
    const float* W     = (const float*)d_in[1];
    const float* lin_b = (const float*)d_in[2];
    const float* a     = (const float*)d_in[3];
    const float* bias  = (const float*)d_in[4];
    float* out = (float*)d_out;

    unsigned int*   Lpp = (unsigned int*)d_ws;                // f16x2 [H][M][64]   (1 MB)
    unsigned int*   Rtp = Lpp + 4 * Mc * 64;                  // f16x2 [16][64][K]  (1 MB)
    float*          eb  = (float*)(Rtp + 16 * 64 * Kc);       // fp32  [16*4][K]    (64 KB)

    k1<<<512, 256, 0, stream>>>(x, W, lin_b, a, Lpp, Rtp, eb);
    k2<<<512, 256, 0, stream>>>(x, a, bias, Lpp, Rtp, eb, out);
}

// Round 12
// 25.190 us; speedup vs baseline: 5.4992x; 1.0491x over previous
//
#include <hip/hip_runtime.h>
#include <math.h>

// B=4, K=256, D=128, H=4, alpha=0.2
// leaky(s) = 0.6*s + 0.4*|s|  (exact for alpha=0.2)
// e_ij = [0.6*(a.Lp_i) cancels in softmax] + 0.6*(a.R_j) + sum_d (0.4 a_d)|Lp_id + R_jd| + bias_ij
// mean_h(P_h @ x) = (mean_h P_h) @ x.
// k1: f16-pair dot2 GEMM (operands packed along k in LDS) -> Lpp/Rtp packed f16.
// k2: fused per-(b,2-row) block over all 4 heads -> P-bar fp32 LDS -> single PV -> out.
constexpr int Kc = 256, Dc = 128, Mc = 1024;    // Mc = B*K

typedef _Float16 h2_t __attribute__((ext_vector_type(2)));
union U32H2 { unsigned int u; h2_t h; };
__device__ inline h2_t u2h(unsigned int u) { U32H2 x; x.u = u; return x.h; }
__device__ inline unsigned int h2u(h2_t h) { U32H2 x; x.h = h; return x.u; }
__device__ inline unsigned int packh(float a, float b) {
    h2_t h; h.x = (_Float16)a; h.y = (_Float16)b; return h2u(h);
}

#if __has_builtin(__builtin_amdgcn_fdot2)
__device__ inline float dot2h(unsigned int a, unsigned int b, float c) {
    return __builtin_amdgcn_fdot2(u2h(a), u2h(b), c, false);
}
#else
__device__ inline float dot2h(unsigned int a, unsigned int b, float c) {
    h2_t ah = u2h(a), bh = u2h(b);
    return fmaf((float)ah.x, (float)bh.x, fmaf((float)ah.y, (float)bh.y, c));
}
#endif

// acc += (0.4a_2d)|l_2d + r_2d| + (0.4a_2d+1)|l_2d+1 + r_2d+1|, f32 accumulate
__device__ inline float estep(unsigned int r, unsigned int l, h2_t av, float acc) {
    h2_t s = u2h(r) + u2h(l);                       // v_pk_add_f16
    unsigned int t = h2u(s) & 0x7FFF7FFFu;          // packed abs
#if __has_builtin(__builtin_amdgcn_fdot2)
    return __builtin_amdgcn_fdot2(u2h(t), av, acc, false);   // v_dot2_f32_f16
#else
    h2_t th = u2h(t);
    return fmaf((float)th.x, (float)av.x, fmaf((float)th.y, (float)av.y, acc));
#endif
}

// ---------------------------------------------------------------------------
// K1 (256 blocks, 256 thr): 64x64-tile GEMM, 4x4 acc, f16-pair dot2 inner loop.
//   bid <  128 : Lpp[h][m][dp] = packed-f16 pair of (x@W_src + lin_b)
//   bid >= 128 : Rtp[hb][dp][j] = packed-f16 pair of (x@W_dst)^T
//                + eb[(hb*2+dt)][j] = 1.5 * sum_{d in 64-slice} 0.4*a_d*R_jd (fp32)
// ---------------------------------------------------------------------------
__global__ __launch_bounds__(256) void k1(const float* __restrict__ x,
                                          const float* __restrict__ W,
                                          const float* __restrict__ lin_b,
                                          const float* __restrict__ a,
                                          unsigned int* __restrict__ Lpp,
                                          unsigned int* __restrict__ Rtp,
                                          float* __restrict__ eb) {
    __shared__ unsigned int As2[64 * 64];   // [k2][m-role] packed k-pairs, 16 KB
    __shared__ unsigned int Bs2[64 * 64];   // [k2][n-role] packed k-pairs, 16 KB
    __shared__ float red[4][16][4];

    const int tid = threadIdx.x;
    const int bid = blockIdx.x;
    const int tx = tid & 15, ty = tid >> 4;   // ty 0..15
    const bool isL = (bid < 128);

    int h, b, m0, n0, dt;
    if (isL) {
        const int nt = bid & 1, mt = (bid >> 1) & 15;
        h = (bid >> 5) & 3; b = 0; dt = 0;
        m0 = mt * 64; n0 = nt * 64;
        // As2 = x rows m0.., packed along k
        {
            const int m_l = tid & 63, kq = tid >> 6;
            #pragma unroll
            for (int c = 0; c < 8; ++c) {
                const float4 v = *(const float4*)&x[(m0 + m_l) * Dc + kq * 32 + c * 4];
                As2[(kq * 16 + c * 2 + 0) * 64 + m_l] = packh(v.x, v.y);
                As2[(kq * 16 + c * 2 + 1) * 64 + m_l] = packh(v.z, v.w);
            }
        }
        // Bs2 = W_src, packed along k (rows)
        {
            const int n_l = tid & 63, kq = tid >> 6;
            const float* Wb = W + (h * 2) * Dc * Dc;
            #pragma unroll
            for (int kk = 0; kk < 16; ++kk) {
                const int k2 = kq * 16 + kk;
                Bs2[k2 * 64 + n_l] =
                    packh(Wb[(2 * k2) * Dc + n0 + n_l], Wb[(2 * k2 + 1) * Dc + n0 + n_l]);
            }
        }
    } else {
        const int r_ = bid - 128;
        const int jt = r_ & 3;
        dt = (r_ >> 2) & 1;
        b  = (r_ >> 3) & 3;
        h  = (r_ >> 5) & 3;
        m0 = dt * 64;          // m-role = d
        n0 = jt * 64;          // n-role = j
        // As2 = W_dst cols d0.., packed along k (rows)
        {
            const int d_l = tid & 63, kq = tid >> 6;
            const float* Wb = W + ((h * 2 + 1) * Dc) * Dc;
            #pragma unroll
            for (int kk = 0; kk < 16; ++kk) {
                const int k2 = kq * 16 + kk;
                As2[k2 * 64 + d_l] =
                    packh(Wb[(2 * k2) * Dc + m0 + d_l], Wb[(2 * k2 + 1) * Dc + m0 + d_l]);
            }
        }
        // Bs2 = x rows b*K + j0.., packed along k
        {
            const int j_l = tid & 63, kq = tid >> 6;
            #pragma unroll
            for (int c = 0; c < 8; ++c) {
                const float4 v = *(const float4*)&x[(b * Kc + n0 + j_l) * Dc + kq * 32 + c * 4];
                Bs2[(kq * 16 + c * 2 + 0) * 64 + j_l] = packh(v.x, v.y);
                Bs2[(kq * 16 + c * 2 + 1) * 64 + j_l] = packh(v.z, v.w);
            }
        }
    }
    __syncthreads();

    float acc[4][4];
    #pragma unroll
    for (int r = 0; r < 4; ++r)
        #pragma unroll
        for (int c = 0; c < 4; ++c) acc[r][c] = 0.f;

    #pragma unroll 8
    for (int k2 = 0; k2 < 64; ++k2) {
        const uint4 xa = *(const uint4*)&As2[k2 * 64 + ty * 4];   // 4 m x k-pair
        const uint4 wb = *(const uint4*)&Bs2[k2 * 64 + tx * 4];   // 4 n x k-pair
        acc[0][0] = dot2h(xa.x, wb.x, acc[0][0]);
        acc[0][1] = dot2h(xa.x, wb.y, acc[0][1]);
        acc[0][2] = dot2h(xa.x, wb.z, acc[0][2]);
        acc[0][3] = dot2h(xa.x, wb.w, acc[0][3]);
        acc[1][0] = dot2h(xa.y, wb.x, acc[1][0]);
        acc[1][1] = dot2h(xa.y, wb.y, acc[1][1]);
        acc[1][2] = dot2h(xa.y, wb.z, acc[1][2]);
        acc[1][3] = dot2h(xa.y, wb.w, acc[1][3]);
        acc[2][0] = dot2h(xa.z, wb.x, acc[2][0]);
        acc[2][1] = dot2h(xa.z, wb.y, acc[2][1]);
        acc[2][2] = dot2h(xa.z, wb.z, acc[2][2]);
        acc[2][3] = dot2h(xa.z, wb.w, acc[2][3]);
        acc[3][0] = dot2h(xa.w, wb.x, acc[3][0]);
        acc[3][1] = dot2h(xa.w, wb.y, acc[3][1]);
        acc[3][2] = dot2h(xa.w, wb.z, acc[3][2]);
        acc[3][3] = dot2h(xa.w, wb.w, acc[3][3]);
    }

    if (isL) {
        const float4 lv = *(const float4*)&lin_b[h * Dc + n0 + tx * 4];
        #pragma unroll
        for (int r = 0; r < 4; ++r) {
            uint2 pk;
            pk.x = packh(acc[r][0] + lv.x, acc[r][1] + lv.y);
            pk.y = packh(acc[r][2] + lv.z, acc[r][3] + lv.w);
            *(uint2*)&Lpp[(h * Mc + m0 + ty * 4 + r) * 64 + (n0 >> 1) + tx * 2] = pk;
        }
    } else {
        // Rtp[hb][dp][j]: pack along d = m-role (rows r of acc)
        #pragma unroll
        for (int rp = 0; rp < 2; ++rp) {
            uint4 pk;
            pk.x = packh(acc[2 * rp][0], acc[2 * rp + 1][0]);
            pk.y = packh(acc[2 * rp][1], acc[2 * rp + 1][1]);
            pk.z = packh(acc[2 * rp][2], acc[2 * rp + 1][2]);
            pk.w = packh(acc[2 * rp][3], acc[2 * rp + 1][3]);
            *(uint4*)&Rtp[((h * 4 + b) * 64 + (m0 >> 1) + ty * 2 + rp) * Kc + n0 + tx * 4] = pk;
        }
        // eb partial: p_c = 0.4 * sum_r a[m0+ty*4+r] * acc[r][c]
        const float4 av = *(const float4*)&a[h * Dc + m0 + ty * 4];
        float p0 = 0.4f * (av.x * acc[0][0] + av.y * acc[1][0] + av.z * acc[2][0] + av.w * acc[3][0]);
        float p1 = 0.4f * (av.x * acc[0][1] + av.y * acc[1][1] + av.z * acc[2][1] + av.w * acc[3][1]);
        float p2 = 0.4f * (av.x * acc[0][2] + av.y * acc[1][2] + av.z * acc[2][2] + av.w * acc[3][2]);
        float p3 = 0.4f * (av.x * acc[0][3] + av.y * acc[1][3] + av.z * acc[2][3] + av.w * acc[3][3]);
        // reduce over the 4 ty values within each wave (tid bits 4..5)
        p0 += __shfl_xor(p0, 16, 64); p0 += __shfl_xor(p0, 32, 64);
        p1 += __shfl_xor(p1, 16, 64); p1 += __shfl_xor(p1, 32, 64);
        p2 += __shfl_xor(p2, 16, 64); p2 += __shfl_xor(p2, 32, 64);
        p3 += __shfl_xor(p3, 16, 64); p3 += __shfl_xor(p3, 32, 64);
        if (((tid >> 4) & 3) == 0) {
            const int w = tid >> 6;
            red[w][tx][0] = p0; red[w][tx][1] = p1;
            red[w][tx][2] = p2; red[w][tx][3] = p3;
        }
        __syncthreads();
        if (tid < 64) {
            const int txl = tid >> 2, c = tid & 3;
            const float v = red[0][txl][c] + red[1][txl][c] + red[2][txl][c] + red[3][txl][c];
            eb[((h * 4 + b) * 2 + dt) * Kc + n0 + tid] = 1.5f * v;
        }
    }
}

// ---------------------------------------------------------------------------
// K2 fused (512 blocks = (b, 128 i-tiles of 2 rows), 256 thr, 2 blk/CU,
// b pinned per XCD): per head h: e-phase (thread (dq,j4) owns acc[2i][4j]
// over a 32-d slice, Rt from global/L2) -> padded-LDS dq-reduce -> wave
// softmax (waves 0,1) -> accumulate P-bar (fp32 LDS).  Then single PV with
// x from global/L2, jq-reduce, write final out.   (R11 champion; only the
// eb segment count changed 4 -> 2.)
// ---------------------------------------------------------------------------
#define E4(ACC, LPV)                               \
    ACC.x = estep(rr.x, LPV, av, ACC.x);           \
    ACC.y = estep(rr.y, LPV, av, ACC.y);           \
    ACC.z = estep(rr.z, LPV, av, ACC.z);           \
    ACC.w = estep(rr.w, LPV, av, ACC.w);

__global__ __launch_bounds__(256) void k2(const float* __restrict__ x,
                                          const float* __restrict__ a,
                                          const float* __restrict__ bias,
                                          const unsigned int* __restrict__ Lpp,
                                          const unsigned int* __restrict__ Rtp,
                                          const float* __restrict__ eb,
                                          float* __restrict__ out) {
    __shared__ float red[256 * 12];          // 12 KB reduce scratch (e-phase, then PV)
    __shared__ unsigned int lpT2[4 * 64 * 2]; // [h][dp][i] 2 KB packed-f16 Lp
    __shared__ unsigned int aa2s[4 * 64];     // [h][dp] packed-f16 0.4*a pairs 1 KB
    __shared__ float plbar[2 * Kc];           // fp32 P-bar accumulator 2 KB

    const int tid = threadIdx.x;
    const int L = blockIdx.x;
    // XCD-pin: L&7 -> XCD; b = xcd>>1 (2 XCDs per b); it from remaining bits.
    const int xcd = L & 7;
    const int b = xcd >> 1;
    const int it = ((L >> 3) << 1) | (xcd & 1);   // 0..127
    const int i0 = it * 2;

    {   // stage lpT2[h][dp][i]: thread -> (h = tid>>6, dp = tid&63), both i rows
        const int h = tid >> 6, dp = tid & 63;
        uint2 v;
        v.x = Lpp[(h * Mc + b * Kc + i0 + 0) * 64 + dp];
        v.y = Lpp[(h * Mc + b * Kc + i0 + 1) * 64 + dp];
        *(uint2*)&lpT2[(h * 64 + dp) * 2] = v;
        aa2s[tid] = packh(0.4f * a[h * Dc + 2 * dp], 0.4f * a[h * Dc + 2 * dp + 1]);
    }
    if (tid < 128) ((float4*)plbar)[tid] = make_float4(0.f, 0.f, 0.f, 0.f);
    __syncthreads();

    const int dq = tid >> 6, j4 = tid & 63;
    const int w = tid >> 6, l = tid & 63;

    #pragma unroll 1
    for (int h = 0; h < 4; ++h) {
        const int hb = h * 4 + b;
        float4 acc0 = make_float4(0.f, 0.f, 0.f, 0.f);
        float4 acc1 = make_float4(0.f, 0.f, 0.f, 0.f);
        {
            const unsigned int* rb = Rtp + (hb * 64 + dq * 16) * Kc + j4 * 4;
            const unsigned int* lt = lpT2 + (h * 64 + dq * 16) * 2;
            const unsigned int* at = aa2s + h * 64 + dq * 16;
            #pragma unroll
            for (int dp = 0; dp < 16; ++dp) {
                const uint4 rr = *(const uint4*)(rb + dp * Kc);    // 4 j x 2 d (global, L2-hot)
                const uint2 lp2 = *(const uint2*)(lt + dp * 2);    // 2 i x 2 d (LDS b64)
                const h2_t av = u2h(at[dp]);                       // LDS b32 broadcast
                E4(acc0, lp2.x);
                E4(acc1, lp2.y);
            }
        }
        {
            float* myred = red + tid * 12;
            *(float4*)&myred[0] = acc0;
            *(float4*)&myred[4] = acc1;
        }
        __syncthreads();

        // softmax: wave w (0,1) owns row i0+w; lane l = j-quad
        if (w < 2) {
            float4 e0 = make_float4(0.f, 0.f, 0.f, 0.f);
            #pragma unroll
            for (int q4 = 0; q4 < 4; ++q4) {
                const float4 v = *(const float4*)&red[(q4 * 64 + l) * 12 + w * 4];
                e0.x += v.x; e0.y += v.y; e0.z += v.z; e0.w += v.w;
            }
            float4 ebs;
            {
                const float4 v0 = *(const float4*)&eb[(hb * 2 + 0) * Kc + l * 4];
                const float4 v1 = *(const float4*)&eb[(hb * 2 + 1) * Kc + l * 4];
                ebs.x = v0.x + v1.x; ebs.y = v0.y + v1.y;
                ebs.z = v0.z + v1.z; ebs.w = v0.w + v1.w;
            }
            const float4 bv = *(const float4*)&bias[(h * Kc + i0 + w) * Kc + l * 4];
            e0.x += ebs.x + bv.x;
            e0.y += ebs.y + bv.y;
            e0.z += ebs.z + bv.z;
            e0.w += ebs.w + bv.w;

            float m = fmaxf(fmaxf(e0.x, e0.y), fmaxf(e0.z, e0.w));
            #pragma unroll
            for (int off = 1; off < 64; off <<= 1) m = fmaxf(m, __shfl_xor(m, off, 64));
            const float p0 = __expf(e0.x - m), p1 = __expf(e0.y - m);
            const float p2 = __expf(e0.z - m), p3 = __expf(e0.w - m);
            float s = p0 + p1 + p2 + p3;
            #pragma unroll
            for (int off = 1; off < 64; off <<= 1) s += __shfl_xor(s, off, 64);
            const float sc = 0.25f / s;     // fold mean over H
            float4 cur = *(float4*)&plbar[w * Kc + l * 4];
            cur.x = fmaf(p0, sc, cur.x);
            cur.y = fmaf(p1, sc, cur.y);
            cur.z = fmaf(p2, sc, cur.z);
            cur.w = fmaf(p3, sc, cur.w);
            *(float4*)&plbar[w * Kc + l * 4] = cur;
        }
        __syncthreads();
    }

    // ---- single PV with P-bar: out[i][d] = sum_j plbar[i][j] * x[b][j][d] ----
    const int jq = tid >> 5, dd4 = tid & 31;
    float4 o0 = make_float4(0.f, 0.f, 0.f, 0.f);
    float4 o1 = make_float4(0.f, 0.f, 0.f, 0.f);
    {
        const float* xb = x + (b * Kc) * Dc + dd4 * 4;
        #pragma unroll 4
        for (int jj = 0; jj < 32; ++jj) {
            const int j = jj * 8 + jq;
            const float4 xv = *(const float4*)(xb + j * Dc);   // global, L2-hot
            const float pv0 = plbar[j];                         // LDS broadcast
            const float pv1 = plbar[Kc + j];
            o0.x = fmaf(pv0, xv.x, o0.x); o0.y = fmaf(pv0, xv.y, o0.y);
            o0.z = fmaf(pv0, xv.z, o0.z); o0.w = fmaf(pv0, xv.w, o0.w);
            o1.x = fmaf(pv1, xv.x, o1.x); o1.y = fmaf(pv1, xv.y, o1.y);
            o1.z = fmaf(pv1, xv.z, o1.z); o1.w = fmaf(pv1, xv.w, o1.w);
        }
    }
    {
        float* myred = red + (jq * 32 + dd4) * 12;
        *(float4*)&myred[0] = o0;
        *(float4*)&myred[4] = o1;
    }
    __syncthreads();
    if (tid < 64) {
        const int i_f = tid >> 5, dd_f = tid & 31;
        float4 s = make_float4(0.f, 0.f, 0.f, 0.f);
        #pragma unroll
        for (int q = 0; q < 8; ++q) {
            const float4 v = *(const float4*)&red[(q * 32 + dd_f) * 12 + i_f * 4];
            s.x += v.x; s.y += v.y; s.z += v.z; s.w += v.w;
        }
        *(float4*)&out[(b * Kc + i0 + i_f) * Dc + dd_f * 4] = s;
    }
}

extern "C" void kernel_launch(void* const* d_in, const int* in_sizes, int n_in,
                              void* d_out, int out_size, void* d_ws, size_t ws_size,
                              hipStream_t stream) {
    const float* x     = (const float*)d_in[0];
    const float* W     = (const float*)d_in[1];
    const float* lin_b = (const float*)d_in[2];
    const float* a     = (const float*)d_in[3];
    const float* bias  = (const float*)d_in[4];
    float* out = (float*)d_out;

    unsigned int*   Lpp = (unsigned int*)d_ws;                // f16x2 [H][M][64]   (1 MB)
    unsigned int*   Rtp = Lpp + 4 * Mc * 64;                  // f16x2 [16][64][K]  (1 MB)
    float*          eb  = (float*)(Rtp + 16 * 64 * Kc);       // fp32  [16*2][K]    (32 KB)

    k1<<<256, 256, 0, stream>>>(x, W, lin_b, a, Lpp, Rtp, eb);
    k2<<<512, 256, 0, stream>>>(x, a, bias, Lpp, Rtp, eb, out);
}

// Round 13
// 23.534 us; speedup vs baseline: 5.8863x; 1.0704x over previous
//
#include <hip/hip_runtime.h>
#include <math.h>

// B=4, K=256, D=128, H=4, alpha=0.2
// leaky(s) = 0.6*s + 0.4*|s|  (exact for alpha=0.2)
// e_ij = [0.6*(a.Lp_i) cancels in softmax] + 0.6*(a.R_j) + sum_d (0.4 a_d)|Lp_id + R_jd| + bias_ij
// mean_h(P_h @ x) = (mean_h P_h) @ x.
// k1: f16-pair dot2 GEMM -> Lpp/Rtp packed f16 + eb (j-only softmax term).
// k2: fused; wave w = head w, thread owns full d=128 for (2i x 4j) -> no cross-thread
//     d-reduce, 4 heads concurrent, P-bar in LDS -> single PV -> out.
constexpr int Kc = 256, Dc = 128, Mc = 1024;    // Mc = B*K

typedef _Float16 h2_t __attribute__((ext_vector_type(2)));
union U32H2 { unsigned int u; h2_t h; };
__device__ inline h2_t u2h(unsigned int u) { U32H2 x; x.u = u; return x.h; }
__device__ inline unsigned int h2u(h2_t h) { U32H2 x; x.h = h; return x.u; }
__device__ inline unsigned int packh(float a, float b) {
    h2_t h; h.x = (_Float16)a; h.y = (_Float16)b; return h2u(h);
}

#if __has_builtin(__builtin_amdgcn_fdot2)
__device__ inline float dot2h(unsigned int a, unsigned int b, float c) {
    return __builtin_amdgcn_fdot2(u2h(a), u2h(b), c, false);
}
#else
__device__ inline float dot2h(unsigned int a, unsigned int b, float c) {
    h2_t ah = u2h(a), bh = u2h(b);
    return fmaf((float)ah.x, (float)bh.x, fmaf((float)ah.y, (float)bh.y, c));
}
#endif

// acc += (0.4a_2d)|l_2d + r_2d| + (0.4a_2d+1)|l_2d+1 + r_2d+1|, f32 accumulate
__device__ inline float estep(unsigned int r, unsigned int l, h2_t av, float acc) {
    h2_t s = u2h(r) + u2h(l);                       // v_pk_add_f16
    unsigned int t = h2u(s) & 0x7FFF7FFFu;          // packed abs
#if __has_builtin(__builtin_amdgcn_fdot2)
    return __builtin_amdgcn_fdot2(u2h(t), av, acc, false);   // v_dot2_f32_f16
#else
    h2_t th = u2h(t);
    return fmaf((float)th.x, (float)av.x, fmaf((float)th.y, (float)av.y, acc));
#endif
}

// ---------------------------------------------------------------------------
// K1 (256 blocks, 256 thr): 64x64-tile GEMM, 4x4 acc, f16-pair dot2 inner loop.
// (byte-identical to R12)
// ---------------------------------------------------------------------------
__global__ __launch_bounds__(256) void k1(const float* __restrict__ x,
                                          const float* __restrict__ W,
                                          const float* __restrict__ lin_b,
                                          const float* __restrict__ a,
                                          unsigned int* __restrict__ Lpp,
                                          unsigned int* __restrict__ Rtp,
                                          float* __restrict__ eb) {
    __shared__ unsigned int As2[64 * 64];   // [k2][m-role] packed k-pairs, 16 KB
    __shared__ unsigned int Bs2[64 * 64];   // [k2][n-role] packed k-pairs, 16 KB
    __shared__ float red[4][16][4];

    const int tid = threadIdx.x;
    const int bid = blockIdx.x;
    const int tx = tid & 15, ty = tid >> 4;   // ty 0..15
    const bool isL = (bid < 128);

    int h, b, m0, n0, dt;
    if (isL) {
        const int nt = bid & 1, mt = (bid >> 1) & 15;
        h = (bid >> 5) & 3; b = 0; dt = 0;
        m0 = mt * 64; n0 = nt * 64;
        {
            const int m_l = tid & 63, kq = tid >> 6;
            #pragma unroll
            for (int c = 0; c < 8; ++c) {
                const float4 v = *(const float4*)&x[(m0 + m_l) * Dc + kq * 32 + c * 4];
                As2[(kq * 16 + c * 2 + 0) * 64 + m_l] = packh(v.x, v.y);
                As2[(kq * 16 + c * 2 + 1) * 64 + m_l] = packh(v.z, v.w);
            }
        }
        {
            const int n_l = tid & 63, kq = tid >> 6;
            const float* Wb = W + (h * 2) * Dc * Dc;
            #pragma unroll
            for (int kk = 0; kk < 16; ++kk) {
                const int k2 = kq * 16 + kk;
                Bs2[k2 * 64 + n_l] =
                    packh(Wb[(2 * k2) * Dc + n0 + n_l], Wb[(2 * k2 + 1) * Dc + n0 + n_l]);
            }
        }
    } else {
        const int r_ = bid - 128;
        const int jt = r_ & 3;
        dt = (r_ >> 2) & 1;
        b  = (r_ >> 3) & 3;
        h  = (r_ >> 5) & 3;
        m0 = dt * 64;          // m-role = d
        n0 = jt * 64;          // n-role = j
        {
            const int d_l = tid & 63, kq = tid >> 6;
            const float* Wb = W + ((h * 2 + 1) * Dc) * Dc;
            #pragma unroll
            for (int kk = 0; kk < 16; ++kk) {
                const int k2 = kq * 16 + kk;
                As2[k2 * 64 + d_l] =
                    packh(Wb[(2 * k2) * Dc + m0 + d_l], Wb[(2 * k2 + 1) * Dc + m0 + d_l]);
            }
        }
        {
            const int j_l = tid & 63, kq = tid >> 6;
            #pragma unroll
            for (int c = 0; c < 8; ++c) {
                const float4 v = *(const float4*)&x[(b * Kc + n0 + j_l) * Dc + kq * 32 + c * 4];
                Bs2[(kq * 16 + c * 2 + 0) * 64 + j_l] = packh(v.x, v.y);
                Bs2[(kq * 16 + c * 2 + 1) * 64 + j_l] = packh(v.z, v.w);
            }
        }
    }
    __syncthreads();

    float acc[4][4];
    #pragma unroll
    for (int r = 0; r < 4; ++r)
        #pragma unroll
        for (int c = 0; c < 4; ++c) acc[r][c] = 0.f;

    #pragma unroll 8
    for (int k2 = 0; k2 < 64; ++k2) {
        const uint4 xa = *(const uint4*)&As2[k2 * 64 + ty * 4];   // 4 m x k-pair
        const uint4 wb = *(const uint4*)&Bs2[k2 * 64 + tx * 4];   // 4 n x k-pair
        acc[0][0] = dot2h(xa.x, wb.x, acc[0][0]);
        acc[0][1] = dot2h(xa.x, wb.y, acc[0][1]);
        acc[0][2] = dot2h(xa.x, wb.z, acc[0][2]);
        acc[0][3] = dot2h(xa.x, wb.w, acc[0][3]);
        acc[1][0] = dot2h(xa.y, wb.x, acc[1][0]);
        acc[1][1] = dot2h(xa.y, wb.y, acc[1][1]);
        acc[1][2] = dot2h(xa.y, wb.z, acc[1][2]);
        acc[1][3] = dot2h(xa.y, wb.w, acc[1][3]);
        acc[2][0] = dot2h(xa.z, wb.x, acc[2][0]);
        acc[2][1] = dot2h(xa.z, wb.y, acc[2][1]);
        acc[2][2] = dot2h(xa.z, wb.z, acc[2][2]);
        acc[2][3] = dot2h(xa.z, wb.w, acc[2][3]);
        acc[3][0] = dot2h(xa.w, wb.x, acc[3][0]);
        acc[3][1] = dot2h(xa.w, wb.y, acc[3][1]);
        acc[3][2] = dot2h(xa.w, wb.z, acc[3][2]);
        acc[3][3] = dot2h(xa.w, wb.w, acc[3][3]);
    }

    if (isL) {
        const float4 lv = *(const float4*)&lin_b[h * Dc + n0 + tx * 4];
        #pragma unroll
        for (int r = 0; r < 4; ++r) {
            uint2 pk;
            pk.x = packh(acc[r][0] + lv.x, acc[r][1] + lv.y);
            pk.y = packh(acc[r][2] + lv.z, acc[r][3] + lv.w);
            *(uint2*)&Lpp[(h * Mc + m0 + ty * 4 + r) * 64 + (n0 >> 1) + tx * 2] = pk;
        }
    } else {
        #pragma unroll
        for (int rp = 0; rp < 2; ++rp) {
            uint4 pk;
            pk.x = packh(acc[2 * rp][0], acc[2 * rp + 1][0]);
            pk.y = packh(acc[2 * rp][1], acc[2 * rp + 1][1]);
            pk.z = packh(acc[2 * rp][2], acc[2 * rp + 1][2]);
            pk.w = packh(acc[2 * rp][3], acc[2 * rp + 1][3]);
            *(uint4*)&Rtp[((h * 4 + b) * 64 + (m0 >> 1) + ty * 2 + rp) * Kc + n0 + tx * 4] = pk;
        }
        const float4 av = *(const float4*)&a[h * Dc + m0 + ty * 4];
        float p0 = 0.4f * (av.x * acc[0][0] + av.y * acc[1][0] + av.z * acc[2][0] + av.w * acc[3][0]);
        float p1 = 0.4f * (av.x * acc[0][1] + av.y * acc[1][1] + av.z * acc[2][1] + av.w * acc[3][1]);
        float p2 = 0.4f * (av.x * acc[0][2] + av.y * acc[1][2] + av.z * acc[2][2] + av.w * acc[3][2]);
        float p3 = 0.4f * (av.x * acc[0][3] + av.y * acc[1][3] + av.z * acc[2][3] + av.w * acc[3][3]);
        p0 += __shfl_xor(p0, 16, 64); p0 += __shfl_xor(p0, 32, 64);
        p1 += __shfl_xor(p1, 16, 64); p1 += __shfl_xor(p1, 32, 64);
        p2 += __shfl_xor(p2, 16, 64); p2 += __shfl_xor(p2, 32, 64);
        p3 += __shfl_xor(p3, 16, 64); p3 += __shfl_xor(p3, 32, 64);
        if (((tid >> 4) & 3) == 0) {
            const int w = tid >> 6;
            red[w][tx][0] = p0; red[w][tx][1] = p1;
            red[w][tx][2] = p2; red[w][tx][3] = p3;
        }
        __syncthreads();
        if (tid < 64) {
            const int txl = tid >> 2, c = tid & 3;
            const float v = red[0][txl][c] + red[1][txl][c] + red[2][txl][c] + red[3][txl][c];
            eb[((h * 4 + b) * 2 + dt) * Kc + n0 + tid] = 1.5f * v;
        }
    }
}

// ---------------------------------------------------------------------------
// K2 fused (512 blocks = (b, 128 i-tiles of 2 rows), 256 thr, 2 blk/CU,
// b pinned per XCD): wave w = head w; thread (w, j4) owns e[2i][4j] over the
// FULL d=128 (64 packed pairs) -> no cross-thread d-reduce, no h-loop.
// Per wave: shuffle softmax of its head's 2 rows -> write 0.25*P to LDS ->
// barrier -> 4-head sum -> P-bar -> single PV -> out.
// ---------------------------------------------------------------------------
#define E4(ACC, LPV)                               \
    ACC.x = estep(rr.x, LPV, av, ACC.x);           \
    ACC.y = estep(rr.y, LPV, av, ACC.y);           \
    ACC.z = estep(rr.z, LPV, av, ACC.z);           \
    ACC.w = estep(rr.w, LPV, av, ACC.w);

__global__ __launch_bounds__(256) void k2(const float* __restrict__ x,
                                          const float* __restrict__ a,
                                          const float* __restrict__ bias,
                                          const unsigned int* __restrict__ Lpp,
                                          const unsigned int* __restrict__ Rtp,
                                          const float* __restrict__ eb,
                                          float* __restrict__ out) {
    __shared__ float red[256 * 12];           // 12 KB: per-head P (4x2x256=2048 fl), then PV scratch
    __shared__ unsigned int lpT2[4 * 64 * 2]; // [h][dp][i] 2 KB packed-f16 Lp
    __shared__ unsigned int aa2s[4 * 64];     // [h][dp] packed-f16 0.4*a pairs 1 KB
    __shared__ float plbar[2 * Kc];           // fp32 P-bar 2 KB

    const int tid = threadIdx.x;
    const int L = blockIdx.x;
    // XCD-pin: L&7 -> XCD; b = xcd>>1 (2 XCDs per b); it from remaining bits.
    const int xcd = L & 7;
    const int b = xcd >> 1;
    const int it = ((L >> 3) << 1) | (xcd & 1);   // 0..127
    const int i0 = it * 2;

    {   // stage lpT2[h][dp][i]: thread -> (h = tid>>6, dp = tid&63), both i rows
        const int hs = tid >> 6, dp = tid & 63;
        uint2 v;
        v.x = Lpp[(hs * Mc + b * Kc + i0 + 0) * 64 + dp];
        v.y = Lpp[(hs * Mc + b * Kc + i0 + 1) * 64 + dp];
        *(uint2*)&lpT2[(hs * 64 + dp) * 2] = v;
        aa2s[tid] = packh(0.4f * a[hs * Dc + 2 * dp], 0.4f * a[hs * Dc + 2 * dp + 1]);
    }
    __syncthreads();

    const int h = tid >> 6, j4 = tid & 63;    // wave = head
    const int hb = h * 4 + b;

    // ---- e-phase: full d in-thread, acc[2 rows][4 j] ----
    float4 acc0 = make_float4(0.f, 0.f, 0.f, 0.f);
    float4 acc1 = make_float4(0.f, 0.f, 0.f, 0.f);
    {
        const unsigned int* rb = Rtp + (hb * 64) * Kc + j4 * 4;
        const unsigned int* lt = lpT2 + (h * 64) * 2;
        const unsigned int* at = aa2s + h * 64;
        #pragma unroll 8
        for (int dp = 0; dp < 64; ++dp) {
            const uint4 rr = *(const uint4*)(rb + dp * Kc);    // 4 j x 2 d (global, L2-hot, 1KB/wave)
            const uint2 lp2 = *(const uint2*)(lt + dp * 2);    // 2 i x 2 d (LDS b64 broadcast)
            const h2_t av = u2h(at[dp]);                       // LDS b32 broadcast
            E4(acc0, lp2.x);
            E4(acc1, lp2.y);
        }
    }

    // ---- epilogue + softmax (wave-local, 2 rows) ----
    {
        float4 ebs;
        {
            const float4 v0 = *(const float4*)&eb[(hb * 2 + 0) * Kc + j4 * 4];
            const float4 v1 = *(const float4*)&eb[(hb * 2 + 1) * Kc + j4 * 4];
            ebs.x = v0.x + v1.x; ebs.y = v0.y + v1.y;
            ebs.z = v0.z + v1.z; ebs.w = v0.w + v1.w;
        }
        const float4 bv0 = *(const float4*)&bias[(h * Kc + i0 + 0) * Kc + j4 * 4];
        const float4 bv1 = *(const float4*)&bias[(h * Kc + i0 + 1) * Kc + j4 * 4];
        acc0.x += ebs.x + bv0.x; acc0.y += ebs.y + bv0.y;
        acc0.z += ebs.z + bv0.z; acc0.w += ebs.w + bv0.w;
        acc1.x += ebs.x + bv1.x; acc1.y += ebs.y + bv1.y;
        acc1.z += ebs.z + bv1.z; acc1.w += ebs.w + bv1.w;

        {
            float m = fmaxf(fmaxf(acc0.x, acc0.y), fmaxf(acc0.z, acc0.w));
            #pragma unroll
            for (int off = 1; off < 64; off <<= 1) m = fmaxf(m, __shfl_xor(m, off, 64));
            const float p0 = __expf(acc0.x - m), p1 = __expf(acc0.y - m);
            const float p2 = __expf(acc0.z - m), p3 = __expf(acc0.w - m);
            float s = p0 + p1 + p2 + p3;
            #pragma unroll
            for (int off = 1; off < 64; off <<= 1) s += __shfl_xor(s, off, 64);
            const float sc = 0.25f / s;     // fold mean over H
            *(float4*)&red[h * 512 + 0 * Kc + j4 * 4] =
                make_float4(p0 * sc, p1 * sc, p2 * sc, p3 * sc);
        }
        {
            float m = fmaxf(fmaxf(acc1.x, acc1.y), fmaxf(acc1.z, acc1.w));
            #pragma unroll
            for (int off = 1; off < 64; off <<= 1) m = fmaxf(m, __shfl_xor(m, off, 64));
            const float p0 = __expf(acc1.x - m), p1 = __expf(acc1.y - m);
            const float p2 = __expf(acc1.z - m), p3 = __expf(acc1.w - m);
            float s = p0 + p1 + p2 + p3;
            #pragma unroll
            for (int off = 1; off < 64; off <<= 1) s += __shfl_xor(s, off, 64);
            const float sc = 0.25f / s;
            *(float4*)&red[h * 512 + 1 * Kc + j4 * 4] =
                make_float4(p0 * sc, p1 * sc, p2 * sc, p3 * sc);
        }
    }
    __syncthreads();

    // ---- P-bar = sum over 4 heads ----
    if (tid < 128) {
        const int r = tid >> 6, c = tid & 63;
        float4 s = make_float4(0.f, 0.f, 0.f, 0.f);
        #pragma unroll
        for (int w4 = 0; w4 < 4; ++w4) {
            const float4 v = *(const float4*)&red[w4 * 512 + r * Kc + c * 4];
            s.x += v.x; s.y += v.y; s.z += v.z; s.w += v.w;
        }
        *(float4*)&plbar[r * Kc + c * 4] = s;
    }
    __syncthreads();

    // ---- single PV with P-bar: out[i][d] = sum_j plbar[i][j] * x[b][j][d] ----
    const int jq = tid >> 5, dd4 = tid & 31;
    float4 o0 = make_float4(0.f, 0.f, 0.f, 0.f);
    float4 o1 = make_float4(0.f, 0.f, 0.f, 0.f);
    {
        const float* xb = x + (b * Kc) * Dc + dd4 * 4;
        #pragma unroll 4
        for (int jj = 0; jj < 32; ++jj) {
            const int j = jj * 8 + jq;
            const float4 xv = *(const float4*)(xb + j * Dc);   // global, L2-hot
            const float pv0 = plbar[j];                         // LDS broadcast
            const float pv1 = plbar[Kc + j];
            o0.x = fmaf(pv0, xv.x, o0.x); o0.y = fmaf(pv0, xv.y, o0.y);
            o0.z = fmaf(pv0, xv.z, o0.z); o0.w = fmaf(pv0, xv.w, o0.w);
            o1.x = fmaf(pv1, xv.x, o1.x); o1.y = fmaf(pv1, xv.y, o1.y);
            o1.z = fmaf(pv1, xv.z, o1.z); o1.w = fmaf(pv1, xv.w, o1.w);
        }
    }
    {
        float* myred = red + (jq * 32 + dd4) * 12;
        *(float4*)&myred[0] = o0;
        *(float4*)&myred[4] = o1;
    }
    __syncthreads();
    if (tid < 64) {
        const int i_f = tid >> 5, dd_f = tid & 31;
        float4 s = make_float4(0.f, 0.f, 0.f, 0.f);
        #pragma unroll
        for (int q = 0; q < 8; ++q) {
            const float4 v = *(const float4*)&red[(q * 32 + dd_f) * 12 + i_f * 4];
            s.x += v.x; s.y += v.y; s.z += v.z; s.w += v.w;
        }
        *(float4*)&out[(b * Kc + i0 + i_f) * Dc + dd_f * 4] = s;
    }
}

extern "C" void kernel_launch(void* const* d_in, const int* in_sizes, int n_in,
                              void* d_out, int out_size, void* d_ws, size_t ws_size,
                              hipStream_t stream) {
    const float* x     = (const float*)d_in[0];
    const float* W     = (const float*)d_in[1];
    const float* lin_b = (const float*)d_in[2];
    const float* a     = (const float*)d_in[3];
    const float* bias  = (const float*)d_in[4];
    float* out = (float*)d_out;

    unsigned int*   Lpp = (unsigned int*)d_ws;                // f16x2 [H][M][64]   (1 MB)
    unsigned int*   Rtp = Lpp + 4 * Mc * 64;                  // f16x2 [16][64][K]  (1 MB)
    float*          eb  = (float*)(Rtp + 16 * 64 * Kc);       // fp32  [16*2][K]    (32 KB)

    k1<<<256, 256, 0, stream>>>(x, W, lin_b, a, Lpp, Rtp, eb);
    k2<<<512, 256, 0, stream>>>(x, a, bias, Lpp, Rtp, eb, out);
}